// Round 10
// baseline (264.743 us; speedup 1.0000x reference)
//
#include <hip/hip_runtime.h>
#include <stdint.h>

#define HH 16
#define DH 64
#define DD 1024
#define PP 1024
#define NNLEN 8192
#define BBATCH 2
#define MM (BBATCH*NNLEN)   // 16384 rows
#define CCHUNK 128          // chunks per (b,h)
#define LCH 64              // chunk length
#define NGRP 16             // scan groups per (b,h)
#define GCH 8               // chunks per group
#define EPSV 1e-6f

typedef unsigned short u16;
typedef __attribute__((ext_vector_type(4))) unsigned short u16x4;
typedef __attribute__((ext_vector_type(8))) unsigned short u16x8;
typedef __attribute__((ext_vector_type(8))) __bf16 bf16x8;
typedef __attribute__((ext_vector_type(4))) float f32x4;

__device__ __forceinline__ u16 f2bf(float f) {
  unsigned x = __float_as_uint(f);
  return (u16)((x + 0x7fffu + ((x >> 16) & 1u)) >> 16);
}
__device__ __forceinline__ float bf2f(u16 u) {
  return __uint_as_float(((unsigned)u) << 16);
}

// async global->LDS, 16B per lane. LDS dest must be wave-uniform base.
__device__ __forceinline__ void gl2lds16(const void* g, void* l) {
  __builtin_amdgcn_global_load_lds(
      reinterpret_cast<__attribute__((address_space(1))) void*>(
          reinterpret_cast<uintptr_t>(g)),
      reinterpret_cast<__attribute__((address_space(3))) void*>(
          reinterpret_cast<uintptr_t>(l)),
      16, 0, 0);
}

// swizzled LDS read of a bf16x8 fragment from a [*][64] u16 tile.
__device__ __forceinline__ bf16x8 ldsw(const u16* base, int row, int col) {
  union { u16x8 u; bf16x8 b; } cv;
  cv.u = *(const u16x8*)&base[row * 64 + (col ^ ((row & 7) << 3))];
  return cv.b;
}

// swizzled LDS read from a [*][32] u16 tile (BK=32 GEMM).
// granule involution: g ^= (row>>1)&3  ->  quads (4t+g)%8 balanced, 2-way max.
__device__ __forceinline__ bf16x8 ldsw32(const u16* base, int row, int col) {
  union { u16x8 u; bf16x8 b; } cv;
  cv.u = *(const u16x8*)&base[row * 32 + (col ^ (((row >> 1) & 3) << 3))];
  return cv.b;
}

// ---------------------------------------------------------------------------
// prep_all (single launch): x convert + 4 weight transposes + Wa transpose
// ---------------------------------------------------------------------------
__global__ __launch_bounds__(256)
void prep_all(const float* __restrict__ x, u16* __restrict__ xb,
              const float* __restrict__ Wq, u16* __restrict__ WqT,
              const float* __restrict__ Wk, u16* __restrict__ WkT,
              const float* __restrict__ Wv, u16* __restrict__ WvT,
              const float* __restrict__ Wo, u16* __restrict__ WoT,
              const float* __restrict__ Wa, u16* __restrict__ WaT) {
  __shared__ float tile[32][33];
  const int bid = blockIdx.x;
  const int tid = threadIdx.x;
  if (bid < 8192) {
    size_t i = ((size_t)bid * 256 + tid) * 8;
    f32x4 a = *(const f32x4*)(x + i);
    f32x4 b = *(const f32x4*)(x + i + 4);
    u16x8 o;
    o[0] = f2bf(a[0]); o[1] = f2bf(a[1]); o[2] = f2bf(a[2]); o[3] = f2bf(a[3]);
    o[4] = f2bf(b[0]); o[5] = f2bf(b[1]); o[6] = f2bf(b[2]); o[7] = f2bf(b[3]);
    *(u16x8*)(xb + i) = o;
    return;
  }
  if (bid < 12288) {
    const int t = (bid - 8192) >> 10;
    const int sub = (bid - 8192) & 1023;
    const float* in = (t == 0) ? Wq : (t == 1) ? Wk : (t == 2) ? Wv : Wo;
    u16* out = (t == 0) ? WqT : (t == 1) ? WkT : (t == 2) ? WvT : WoT;
    const int bx = (sub & 31) * 32, by = (sub >> 5) * 32;
    const int tx = tid & 31, ty = tid >> 5;
    for (int i2 = ty; i2 < 32; i2 += 8)
      tile[i2][tx] = in[(size_t)(by + i2) * 1024 + bx + tx];
    __syncthreads();
    for (int i2 = ty; i2 < 32; i2 += 8)
      out[(size_t)(bx + i2) * 1024 + by + tx] = f2bf(tile[tx][i2]);
    return;
  }
  {
    int idx = (bid - 12288) * 256 + tid;
    WaT[idx] = f2bf(Wa[(idx & 1023) * 16 + (idx >> 10)]);
  }
}

// ---------------------------------------------------------------------------
// a_proj (MFMA skinny GEMM): abuf = sigmoid(xb @ Wa + ba + 2), M=16384 N=16
// ---------------------------------------------------------------------------
__global__ __launch_bounds__(256)
void a_proj(const u16* __restrict__ xb, const u16* __restrict__ WaT,
            const float* __restrict__ ba, float* __restrict__ abuf) {
  __shared__ __align__(16) u16 As[256 * 32];
  __shared__ __align__(16) u16 Bs[16 * 32];
  const int tid = threadIdx.x;
  const int brow = blockIdx.x * 256;
  const int l = tid & 63, wid = tid >> 6;
  const int la = l & 15, kb8 = (l >> 4) * 8;
  const int sr = tid >> 2, se = (tid & 3) * 8;

  f32x4 acc[4];
#pragma unroll
  for (int mi = 0; mi < 4; ++mi) acc[mi] = (f32x4){0.f, 0.f, 0.f, 0.f};

  for (int kt = 0; kt < 32; ++kt) {
    const int k0 = kt * 32;
    __syncthreads();
#pragma unroll
    for (int i = 0; i < 4; ++i)
      gl2lds16(xb + (size_t)(brow + i * 64 + sr) * DD + k0 + se,
               &As[i * 2048 + wid * 512]);
    if (wid == 0)
      gl2lds16(WaT + (size_t)(l >> 2) * DD + k0 + (l & 3) * 8, &Bs[0]);
    __syncthreads();
    union { u16x8 u; bf16x8 b; } cvb;
    cvb.u = *(const u16x8*)&Bs[la * 32 + kb8];
#pragma unroll
    for (int mi = 0; mi < 4; ++mi) {
      union { u16x8 u; bf16x8 b; } cva;
      cva.u = *(const u16x8*)&As[(wid * 64 + mi * 16 + la) * 32 + kb8];
      acc[mi] = __builtin_amdgcn_mfma_f32_16x16x32_bf16(cva.b, cvb.b, acc[mi], 0, 0, 0);
    }
  }
  const float bav = ba[la];
#pragma unroll
  for (int mi = 0; mi < 4; ++mi)
#pragma unroll
    for (int rr = 0; rr < 4; ++rr) {
      int row = brow + wid * 64 + mi * 16 + ((l >> 4) << 2) + rr;
      float t = acc[mi][rr] + bav + 2.0f;
      abuf[(size_t)row * HH + la] = 1.f / (1.f + __expf(-t));
    }
}

// ---------------------------------------------------------------------------
// bf16 MFMA GEMM, 2-blocks/CU variant: 256x128 tile, BK=32, 8 waves
// (wave-tile 64x64, acc=64 regs), 48KiB LDS dbuf, launch_bounds(512,4)
// -> 4 waves/SIMD from two INDEPENDENT blocks (async barriers -> LDS/MFMA
// overlap across blocks, m114). Same verified minimal-barrier stage-first
// schedule: stage next tile first, one vmcnt(0)+s_barrier per K-tile.
// New granule swizzle for 64B rows: g ^= (row>>1)&3 (conflict-free).
// ROUTE=1: fused QKV (N=3072) routed bf16 epilogue w/ elu+1 on q/k.
// ROUTE=0: f32 output.  NCT = col-tile count (N/128).
// ---------------------------------------------------------------------------
template<int NCT, int ROUTE>
__global__ __launch_bounds__(512, 4)
void gemm_tb(const u16* __restrict__ A, const u16* __restrict__ Bt,
             void* __restrict__ Cout) {
  __shared__ __align__(16) u16 As[2][256 * 32];
  __shared__ __align__(16) u16 Bs[2][128 * 32];
  const int tid = threadIdx.x;
  const int nwg = gridDim.x;
  const int f = blockIdx.x;
  const int swz = (f & 7) * (nwg >> 3) + (f >> 3);
  const int brow = (swz / NCT) * 256;
  const int bcol = (swz % NCT) * 128;
  const int l = tid & 63;
  const int wid = tid >> 6;            // 0..7
  const int wrow = (wid >> 1) * 64;    // 4 M groups
  const int wcol = (wid & 1) * 64;     // 2 N groups
  const int la = l & 15, kb8 = (l >> 4) * 8;
  const int K = 1024;
  const int srow = l >> 2;                                   // 0..15 in chunk
  const int scol = (((l & 3) ^ ((l >> 3) & 3)) << 3);        // pre-swizzled col

  f32x4 acc[4][4];
#pragma unroll
  for (int i = 0; i < 4; ++i)
#pragma unroll
    for (int j = 0; j < 4; ++j) acc[i][j] = (f32x4){0.f, 0.f, 0.f, 0.f};

  // prologue: stage K-tile 0 into buf 0 (A: 16 chunks of 16 rows; B: 8)
#pragma unroll
  for (int j = 0; j < 2; ++j) {
    const int r0 = (wid * 2 + j) * 16 + srow;
    gl2lds16(A + (size_t)(brow + r0) * K + scol, &As[0][(wid * 2 + j) * 512]);
  }
  gl2lds16(Bt + (size_t)(bcol + wid * 16 + srow) * K + scol, &Bs[0][wid * 512]);
  asm volatile("s_waitcnt vmcnt(0)" ::: "memory");
  __builtin_amdgcn_s_barrier();

  const int NKT = K / 32;
  for (int kt = 0; kt < NKT; ++kt) {
    const u16* lA = As[kt & 1];
    const u16* lB = Bs[kt & 1];
    u16* nA = As[(kt + 1) & 1];
    u16* nB = Bs[(kt + 1) & 1];
    const int knext = (kt + 1) * 32;
    const bool more = (kt + 1 < NKT);

    // stage next K-tile FIRST (full tile of compute covers latency)
    if (more) {
#pragma unroll
      for (int j = 0; j < 2; ++j) {
        const int r0 = (wid * 2 + j) * 16 + srow;
        gl2lds16(A + (size_t)(brow + r0) * K + knext + scol,
                 nA + (wid * 2 + j) * 512);
      }
      gl2lds16(Bt + (size_t)(bcol + wid * 16 + srow) * K + knext + scol,
               nB + wid * 512);
    }

    bf16x8 bfr[4];
#pragma unroll
    for (int n2 = 0; n2 < 4; ++n2)
      bfr[n2] = ldsw32(lB, wcol + n2 * 16 + la, kb8);

    __builtin_amdgcn_s_setprio(1);
#pragma unroll
    for (int m2 = 0; m2 < 4; ++m2) {
      bf16x8 afm = ldsw32(lA, wrow + m2 * 16 + la, kb8);
#pragma unroll
      for (int n2 = 0; n2 < 4; ++n2)
        acc[m2][n2] = __builtin_amdgcn_mfma_f32_16x16x32_bf16(
            afm, bfr[n2], acc[m2][n2], 0, 0, 0);
    }
    __builtin_amdgcn_s_setprio(0);

    if (more) {
      asm volatile("s_waitcnt vmcnt(0)" ::: "memory");
      __builtin_amdgcn_s_barrier();
    }
  }

  if (ROUTE) {
    u16* base = (u16*)Cout + (size_t)(bcol >> 10) * ((size_t)MM * 1024);
    const bool act = (bcol < 2048);
#pragma unroll
    for (int mi = 0; mi < 4; ++mi)
#pragma unroll
      for (int ni = 0; ni < 4; ++ni)
#pragma unroll
        for (int rr = 0; rr < 4; ++rr) {
          int row = brow + wrow + mi * 16 + ((l >> 4) << 2) + rr;
          int c2 = (bcol & 1023) + wcol + ni * 16 + la;
          float v = acc[mi][ni][rr];
          if (act) v = v > 0.f ? v + 1.f : __expf(v);
          base[(size_t)row * 1024 + c2] = f2bf(v);
        }
  } else {
#pragma unroll
    for (int mi = 0; mi < 4; ++mi)
#pragma unroll
      for (int ni = 0; ni < 4; ++ni)
#pragma unroll
        for (int rr = 0; rr < 4; ++rr) {
          int row = brow + wrow + mi * 16 + ((l >> 4) << 2) + rr;
          int col = bcol + wcol + ni * 16 + la;
          ((float*)Cout)[(size_t)row * 1024 + col] = acc[mi][ni][rr];
        }
  }
}

// ---------------------------------------------------------------------------
// FUSED Kernel A + scan level 1, cA-hoisted + k/v software pipeline.
// ---------------------------------------------------------------------------
__global__ __launch_bounds__(256)
void chunk_local_scan(const u16* __restrict__ kb, const u16* __restrict__ vb,
                      const float* __restrict__ abuf,
                      u16* __restrict__ Sbuf, float* __restrict__ zbuf,
                      float* __restrict__ cAbuf,
                      float* __restrict__ GAgg, float* __restrict__ zGAgg,
                      float* __restrict__ dpbuf) {
  const int g = blockIdx.x & (NGRP - 1);
  const int bh = blockIdx.x >> 4;
  const int h = bh & (HH - 1);
  const int b = bh >> 4;
  __shared__ __align__(16) u16 KT[64 * 64];   // KT[dk][t] = w_t*k (swizzled)
  __shared__ __align__(16) u16 VTl[64 * 64];  // VTl[dv][t] (swizzled)
  __shared__ float wshA[GCH][64];
  __shared__ float dchA[GCH];
  const int tid = threadIdx.x;
  const int r = tid >> 2, e = (tid & 3) * 16;
  const int l = tid & 63, w = tid >> 6;
  const int kb8 = (l >> 4) << 3, la = l & 15;
  const int dw = 16 * w + ((l >> 4) << 2);
  const int dkz = tid >> 2, tqz = (tid & 3) * 16, swkz = (dkz & 7) << 3;
  const int c0 = g * GCH;
  const int rowbase0 = b * NNLEN + c0 * LCH;

  // hoisted cA prefix scans: wave w handles chunks 2w, 2w+1 (all waves busy)
#pragma unroll
  for (int ii = 0; ii < 2; ++ii) {
    const int i = w * 2 + ii;
    const int blkc = bh * CCHUNK + c0 + i;
    float v = __logf(abuf[(size_t)(rowbase0 + i * LCH + l) * HH + h]);
#pragma unroll
    for (int d = 1; d < 64; d <<= 1) {
      float u = __shfl_up(v, d);
      if (l >= d) v += u;
    }
    cAbuf[(size_t)blkc * 64 + l] = v;
    float tot = __shfl(v, 63);
    wshA[i][l] = __expf(tot - v);
    if (l == 0) dchA[i] = __expf(tot);
  }
  __syncthreads();
  if (tid == 0) {
    float rp = 1.f;
#pragma unroll
    for (int i = 0; i < GCH; ++i) {
      dpbuf[bh * CCHUNK + c0 + i] = rp;
      rp *= dchA[i];
    }
  }

  f32x4 run[4];
#pragma unroll
  for (int ni = 0; ni < 4; ++ni) run[ni] = (f32x4){0.f, 0.f, 0.f, 0.f};
  float zrun = 0.f;

  // preload chunk 0 k/v
  const u16* kp = kb + (size_t)(rowbase0 + r) * PP + h * DH + e;
  const u16* vp = vb + (size_t)(rowbase0 + r) * PP + h * DH + e;
  u16x8 k0 = *(const u16x8*)kp, k1 = *(const u16x8*)(kp + 8);
  u16x8 v0 = *(const u16x8*)vp, v1 = *(const u16x8*)(vp + 8);

  for (int i = 0; i < GCH; ++i) {
    const int blkc = bh * CCHUNK + c0 + i;
    if (i) __syncthreads();             // prior iter's KT/VTl reads done

    {
      const float wt = wshA[i][r];
#pragma unroll
      for (int j = 0; j < 8; ++j) {
        int d0 = e + j, d1 = e + 8 + j;
        KT[d0 * 64 + (r ^ ((d0 & 7) << 3))] = f2bf(bf2f(k0[j]) * wt);
        KT[d1 * 64 + (r ^ ((d1 & 7) << 3))] = f2bf(bf2f(k1[j]) * wt);
        VTl[d0 * 64 + (r ^ ((d0 & 7) << 3))] = v0[j];
        VTl[d1 * 64 + (r ^ ((d1 & 7) << 3))] = v1[j];
      }
    }
    __syncthreads();                    // KT/VTl ready

    // issue next chunk's k/v loads (land during MFMA + epilogue)
    if (i + 1 < GCH) {
      const int rb = rowbase0 + (i + 1) * LCH;
      kp = kb + (size_t)(rb + r) * PP + h * DH + e;
      vp = vb + (size_t)(rb + r) * PP + h * DH + e;
      k0 = *(const u16x8*)kp; k1 = *(const u16x8*)(kp + 8);
      v0 = *(const u16x8*)vp; v1 = *(const u16x8*)(vp + 8);
    }

    const float dch = dchA[i];
    f32x4 s[4];
#pragma unroll
    for (int ni = 0; ni < 4; ++ni) s[ni] = (f32x4){0.f, 0.f, 0.f, 0.f};
#pragma unroll
    for (int kk = 0; kk < 2; ++kk) {
      bf16x8 av = ldsw(VTl, 16 * w + la, kk * 32 + kb8);
#pragma unroll
      for (int ni = 0; ni < 4; ++ni)
        s[ni] = __builtin_amdgcn_mfma_f32_16x16x32_bf16(
            av, ldsw(KT, 16 * ni + la, kk * 32 + kb8), s[ni], 0, 0, 0);
    }

    // write within-group prefix (state BEFORE this chunk), then update
    u16* Sc = Sbuf + (size_t)blkc * 4096;
#pragma unroll
    for (int ni = 0; ni < 4; ++ni)
#pragma unroll
      for (int rr = 0; rr < 4; ++rr)
        Sc[(dw + rr) * 64 + 16 * ni + la] = f2bf(run[ni][rr]);
#pragma unroll
    for (int ni = 0; ni < 4; ++ni)
#pragma unroll
      for (int rr = 0; rr < 4; ++rr)
        run[ni][rr] = dch * run[ni][rr] + s[ni][rr];

    // z: zp[dk] = sum_t w_t k[t][dk]
    {
      float zp = 0.f;
#pragma unroll
      for (int i2 = 0; i2 < 16; ++i2)
        zp += bf2f(KT[dkz * 64 + ((tqz + i2) ^ swkz)]);
      zp += __shfl_xor(zp, 1);
      zp += __shfl_xor(zp, 2);
      if ((tid & 3) == 0) zbuf[(size_t)blkc * 64 + dkz] = zrun;
      zrun = dch * zrun + zp;
    }
  }

  // group aggregates
  float* Ga = GAgg + ((size_t)bh * NGRP + g) * 4096;
#pragma unroll
  for (int ni = 0; ni < 4; ++ni)
#pragma unroll
    for (int rr = 0; rr < 4; ++rr)
      Ga[(dw + rr) * 64 + 16 * ni + la] = run[ni][rr];
  if ((tid & 3) == 0)
    zGAgg[((size_t)bh * NGRP + g) * 64 + dkz] = zrun;
}

// ---------------------------------------------------------------------------
// Scan level 2: across the 16 group aggregates. GAgg(f32) -> GBeg (bf16).
// ---------------------------------------------------------------------------
__global__ __launch_bounds__(1024)
void scan_top(const float* __restrict__ GAgg, u16* __restrict__ GBeg,
              float* __restrict__ zGAgg, const float* __restrict__ cAbuf) {
  const int bh = blockIdx.x;
  const size_t cb = (size_t)bh * CCHUNK;
  __shared__ float Dsh[NGRP];
  if (threadIdx.x < NGRP) {
    float s = 0.f;
#pragma unroll
    for (int i = 0; i < GCH; ++i)
      s += cAbuf[(cb + threadIdx.x * GCH + i) * 64 + 63];
    Dsh[threadIdx.x] = __expf(s);
  }
  __syncthreads();
  const int elem = threadIdx.x * 4;
  const float* base = GAgg + (size_t)bh * NGRP * 4096;
  u16* gb = GBeg + (size_t)bh * NGRP * 4096;
  f32x4 run = (f32x4){0.f, 0.f, 0.f, 0.f};
  f32x4 cur = *(const f32x4*)&base[elem];
#pragma unroll
  for (int gg = 0; gg < NGRP; ++gg) {
    f32x4 nxt;
    if (gg + 1 < NGRP) nxt = *(const f32x4*)&base[(gg + 1) * 4096 + elem];
    u16x4 o;
#pragma unroll
    for (int jj = 0; jj < 4; ++jj) o[jj] = f2bf(run[jj]);
    *(u16x4*)&gb[gg * 4096 + elem] = o;
    const float D = Dsh[gg];
#pragma unroll
    for (int jj = 0; jj < 4; ++jj) run[jj] = D * run[jj] + cur[jj];
    cur = nxt;
  }
  if (threadIdx.x < 64) {
    float* zb = zGAgg + (size_t)bh * NGRP * 64;
    float zr = 0.f;
#pragma unroll
    for (int gg = 0; gg < NGRP; ++gg) {
      float a = zb[gg * 64 + threadIdx.x];
      zb[gg * 64 + threadIdx.x] = zr;
      zr = Dsh[gg] * zr + a;
    }
  }
}

// ---------------------------------------------------------------------------
// Kernel C (MFMA): per-chunk output.
// S0 = prefix(bf16) + dp * Gbegin(bf16);  z0 = zprefix + dp * zGbegin
// ---------------------------------------------------------------------------
__global__ __launch_bounds__(256)
void chunk_out(u16* __restrict__ qb, const u16* __restrict__ kb,
               const u16* __restrict__ vb, const u16* __restrict__ Sbuf,
               const float* __restrict__ zbuf, const float* __restrict__ cAbuf,
               const u16* __restrict__ GBeg, const float* __restrict__ zGAgg,
               const float* __restrict__ dpbuf) {
  const int blk = blockIdx.x;
  const int c = blk & (CCHUNK - 1);
  const int h = (blk >> 7) & (HH - 1);
  const int b = blk >> 11;
  const int bh = blk >> 7;
  const int g = c >> 3;
  const int rowbase = b * NNLEN + c * LCH;

  __shared__ __align__(16) u16 Qs[64 * 64];
  __shared__ __align__(16) u16 Ke[64 * 64];   // Ke, later reused as P tile
  __shared__ __align__(16) u16 VT[64 * 64];
  __shared__ __align__(16) u16 STs[64 * 64];
  __shared__ float cAsh[64], zsh[64], denP[64], qzs[64];

  const int tid = threadIdx.x;
  const int r = tid >> 2, e = (tid & 3) * 16;
  const float dp = dpbuf[blk];

  const u16* qp = qb + (size_t)(rowbase + r) * PP + h * DH + e;
  const u16* kp = kb + (size_t)(rowbase + r) * PP + h * DH + e;
  const u16* vp = vb + (size_t)(rowbase + r) * PP + h * DH + e;
  u16x8 q0 = *(const u16x8*)qp, q1 = *(const u16x8*)(qp + 8);
  u16x8 k0 = *(const u16x8*)kp, k1 = *(const u16x8*)(kp + 8);
  u16x8 v0 = *(const u16x8*)vp, v1 = *(const u16x8*)(vp + 8);
  const u16* sp = Sbuf + (size_t)blk * 4096 + r * 64 + e;
  u16x8 p0 = *(const u16x8*)sp, p1 = *(const u16x8*)(sp + 8);
  const u16* gp = GBeg + ((size_t)bh * NGRP + g) * 4096 + r * 64 + e;
  u16x8 gb0 = *(const u16x8*)gp, gb1 = *(const u16x8*)(gp + 8);
  if (tid < 64) {
    cAsh[tid] = cAbuf[(size_t)blk * 64 + tid];
    zsh[tid] = zbuf[(size_t)blk * 64 + tid]
             + dp * zGAgg[((size_t)bh * NGRP + g) * 64 + tid];
  }
  __syncthreads();

  {
    const float c0c = cAsh[31];
    const int sw = (r & 7) << 3;
    const float qsc = __expf(cAsh[r] - c0c);
    const float ksc = __expf(c0c - cAsh[r]);
    const float ssc = __expf(c0c);
    u16x8 t0, t1, u0, u1, w0, w1;
#pragma unroll
    for (int j = 0; j < 8; ++j) {
      t0[j] = f2bf(bf2f(q0[j]) * qsc);
      t1[j] = f2bf(bf2f(q1[j]) * qsc);
      u0[j] = f2bf(bf2f(k0[j]) * ksc);
      u1[j] = f2bf(bf2f(k1[j]) * ksc);
    }
#pragma unroll
    for (int j = 0; j < 8; ++j) {
      w0[j] = f2bf((bf2f(p0[j]) + dp * bf2f(gb0[j])) * ssc);
      w1[j] = f2bf((bf2f(p1[j]) + dp * bf2f(gb1[j])) * ssc);
    }
    *(u16x8*)&Qs[r * 64 + (e ^ sw)] = t0;
    *(u16x8*)&Qs[r * 64 + ((e + 8) ^ sw)] = t1;
    *(u16x8*)&Ke[r * 64 + (e ^ sw)] = u0;
    *(u16x8*)&Ke[r * 64 + ((e + 8) ^ sw)] = u1;
    *(u16x8*)&STs[r * 64 + (e ^ sw)] = w0;
    *(u16x8*)&STs[r * 64 + ((e + 8) ^ sw)] = w1;
#pragma unroll
    for (int j = 0; j < 8; ++j) {
      int d0 = e + j, d1 = e + 8 + j;
      VT[d0 * 64 + (r ^ ((d0 & 7) << 3))] = v0[j];
      VT[d1 * 64 + (r ^ ((d1 & 7) << 3))] = v1[j];
    }
    if (tid < 64) zsh[tid] *= ssc;
  }
  __syncthreads();

  const int l = tid & 63, w = tid >> 6;
  const int kb8 = (l >> 4) << 3, la = l & 15;

  // --- MFMA1: P = Qe @ Ke^T ---
  bf16x8 aq[2];
  f32x4 p[4];
#pragma unroll
  for (int ni = 0; ni < 4; ++ni) p[ni] = (f32x4){0.f, 0.f, 0.f, 0.f};
#pragma unroll
  for (int kk = 0; kk < 2; ++kk) {
    aq[kk] = ldsw(Qs, 16 * w + la, kk * 32 + kb8);
#pragma unroll
    for (int ni = 0; ni < 4; ++ni)
      p[ni] = __builtin_amdgcn_mfma_f32_16x16x32_bf16(
          aq[kk], ldsw(Ke, 16 * ni + la, kk * 32 + kb8), p[ni], 0, 0, 0);
  }

  const int tw = 16 * w + ((l >> 4) << 2);
  float rsum[4] = {0.f, 0.f, 0.f, 0.f};
#pragma unroll
  for (int ni = 0; ni < 4; ++ni)
#pragma unroll
    for (int rr = 0; rr < 4; ++rr) {
      int s = 16 * ni + la, t = tw + rr;
      float v = (s <= t) ? p[ni][rr] : 0.f;
      p[ni][rr] = v;
      rsum[rr] += v;
    }
#pragma unroll
  for (int d = 1; d < 16; d <<= 1)
#pragma unroll
    for (int rr = 0; rr < 4; ++rr) rsum[rr] += __shfl_xor(rsum[rr], d);
  if (la == 0)
#pragma unroll
    for (int rr = 0; rr < 4; ++rr) denP[tw + rr] = rsum[rr];

  // qz[row] = Qe[row] . z0e from register fragments
  {
    float qzp = 0.f;
#pragma unroll
    for (int kk = 0; kk < 2; ++kk)
#pragma unroll
      for (int j = 0; j < 8; ++j) {
        union { bf16x8 b; u16x8 u; } cv; cv.b = aq[kk];
        qzp += bf2f(cv.u[j]) * zsh[kk * 32 + kb8 + j];
      }
    qzp += __shfl_xor(qzp, 16);
    qzp += __shfl_xor(qzp, 32);
    if (l < 16) qzs[16 * w + la] = qzp;
  }
  __syncthreads();   // all waves done reading Qs/Ke -> Ke reusable as P

  // write P into (dead) Ke tile, swizzled
#pragma unroll
  for (int ni = 0; ni < 4; ++ni)
#pragma unroll
    for (int rr = 0; rr < 4; ++rr) {
      int t = tw + rr, s = 16 * ni + la;
      Ke[t * 64 + (s ^ ((t & 7) << 3))] = f2bf(p[ni][rr]);
    }
  __syncthreads();

  // --- MFMA2: O = P@V + Qe@S0e^T ---
  f32x4 o[4];
#pragma unroll
  for (int ni = 0; ni < 4; ++ni) o[ni] = (f32x4){0.f, 0.f, 0.f, 0.f};
#pragma unroll
  for (int kk = 0; kk < 2; ++kk) {
    bf16x8 ap = ldsw(Ke, 16 * w + la, kk * 32 + kb8);
#pragma unroll
    for (int ni = 0; ni < 4; ++ni)
      o[ni] = __builtin_amdgcn_mfma_f32_16x16x32_bf16(
          ap, ldsw(VT, 16 * ni + la, kk * 32 + kb8), o[ni], 0, 0, 0);
  }
#pragma unroll
  for (int kk = 0; kk < 2; ++kk)
#pragma unroll
    for (int ni = 0; ni < 4; ++ni)
      o[ni] = __builtin_amdgcn_mfma_f32_16x16x32_bf16(
          aq[kk], ldsw(STs, 16 * ni + la, kk * 32 + kb8), o[ni], 0, 0, 0);

  float dn[4];
#pragma unroll
  for (int rr = 0; rr < 4; ++rr) dn[rr] = qzs[tw + rr] + denP[tw + rr] + EPSV;
#pragma unroll
  for (int ni = 0; ni < 4; ++ni)
#pragma unroll
    for (int rr = 0; rr < 4; ++rr) {
      int t = tw + rr, dv = 16 * ni + la;
      qb[(size_t)(rowbase + t) * PP + h * DH + dv] = f2bf(o[ni][rr] / dn[rr]);
    }
}

// ---------------------------------------------------------------------------
extern "C" void kernel_launch(void* const* d_in, const int* in_sizes, int n_in,
                              void* d_out, int out_size, void* d_ws, size_t ws_size,
                              hipStream_t stream) {
  const float* x  = (const float*)d_in[0];
  const float* Wq = (const float*)d_in[1];
  const float* Wk = (const float*)d_in[2];
  const float* Wv = (const float*)d_in[3];
  const float* Wo = (const float*)d_in[4];
  const float* Wa = (const float*)d_in[5];
  const float* ba = (const float*)d_in[6];

  char* ws = (char*)d_ws;
  size_t off = 0;
  auto carve = [&](size_t bytes) {
    void* p = ws + off;
    off += (bytes + 255) & ~(size_t)255;
    return p;
  };
  u16* xb   = (u16*)carve((size_t)MM * DD * 2);
  u16* WqT  = (u16*)carve((size_t)PP * DD * 2);  // WqT/WkT/WvT contiguous
  u16* WkT  = (u16*)carve((size_t)PP * DD * 2);
  u16* WvT  = (u16*)carve((size_t)PP * DD * 2);
  u16* WoT  = (u16*)carve((size_t)DD * PP * 2);
  u16* WaT  = (u16*)carve((size_t)HH * DD * 2);
  u16* qb   = (u16*)carve((size_t)MM * PP * 2);  // qb/kb/vb contiguous
  u16* kb   = (u16*)carve((size_t)MM * PP * 2);
  u16* vb   = (u16*)carve((size_t)MM * PP * 2);
  float* abuf  = (float*)carve((size_t)MM * HH * 4);
  u16*  Sbuf   = (u16*)carve((size_t)BBATCH * HH * CCHUNK * 4096 * 2);
  float* zbuf  = (float*)carve((size_t)BBATCH * HH * CCHUNK * 64 * 4);
  float* cAbuf = (float*)carve((size_t)BBATCH * HH * CCHUNK * 64 * 4);
  float* GAgg  = (float*)carve((size_t)BBATCH * HH * NGRP * 4096 * 4);
  u16*  GBeg   = (u16*)carve((size_t)BBATCH * HH * NGRP * 4096 * 2);
  float* zGAgg = (float*)carve((size_t)BBATCH * HH * NGRP * 64 * 4);
  float* dpbuf = (float*)carve((size_t)BBATCH * HH * CCHUNK * 4);

  prep_all<<<12352, 256, 0, stream>>>(x, xb, Wq, WqT, Wk, WkT, Wv, WvT,
                                      Wo, WoT, Wa, WaT);
  a_proj<<<MM / 256, 256, 0, stream>>>(xb, WaT, ba, abuf);

  // fused QKV: M=16384, N=3072 (WqT/WkT/WvT contiguous), routed epilogue
  gemm_tb<24, 1><<<(MM / 256) * 24, 512, 0, stream>>>(xb, WqT, qb);

  chunk_local_scan<<<BBATCH * HH * NGRP, 256, 0, stream>>>(
      kb, vb, abuf, Sbuf, zbuf, cAbuf, GAgg, zGAgg, dpbuf);
  scan_top<<<BBATCH * HH, 1024, 0, stream>>>(GAgg, GBeg, zGAgg, cAbuf);
  chunk_out<<<BBATCH * HH * CCHUNK, 256, 0, stream>>>(qb, kb, vb, Sbuf, zbuf, cAbuf,
                                                      GBeg, zGAgg, dpbuf);

  gemm_tb<8, 0><<<(MM / 256) * 8, 512, 0, stream>>>(qb, WoT, (float*)d_out);
}

// Round 11
// 258.444 us; speedup vs baseline: 1.0244x; 1.0244x over previous
//
#include <hip/hip_runtime.h>
#include <stdint.h>

#define HH 16
#define DH 64
#define DD 1024
#define PP 1024
#define NNLEN 8192
#define BBATCH 2
#define MM (BBATCH*NNLEN)   // 16384 rows
#define CCHUNK 128          // chunks per (b,h)
#define LCH 64              // chunk length
#define NGRP 16             // scan groups per (b,h)
#define GCH 8               // chunks per group
#define EPSV 1e-6f

typedef unsigned short u16;
typedef __attribute__((ext_vector_type(4))) unsigned short u16x4;
typedef __attribute__((ext_vector_type(8))) unsigned short u16x8;
typedef __attribute__((ext_vector_type(8))) __bf16 bf16x8;
typedef __attribute__((ext_vector_type(4))) float f32x4;

__device__ __forceinline__ u16 f2bf(float f) {
  unsigned x = __float_as_uint(f);
  return (u16)((x + 0x7fffu + ((x >> 16) & 1u)) >> 16);
}
__device__ __forceinline__ float bf2f(u16 u) {
  return __uint_as_float(((unsigned)u) << 16);
}

// async global->LDS, 16B per lane. LDS dest must be wave-uniform base.
__device__ __forceinline__ void gl2lds16(const void* g, void* l) {
  __builtin_amdgcn_global_load_lds(
      reinterpret_cast<__attribute__((address_space(1))) void*>(
          reinterpret_cast<uintptr_t>(g)),
      reinterpret_cast<__attribute__((address_space(3))) void*>(
          reinterpret_cast<uintptr_t>(l)),
      16, 0, 0);
}

// swizzled LDS read of a bf16x8 fragment from a [*][64] u16 tile.
__device__ __forceinline__ bf16x8 ldsw(const u16* base, int row, int col) {
  union { u16x8 u; bf16x8 b; } cv;
  cv.u = *(const u16x8*)&base[row * 64 + (col ^ ((row & 7) << 3))];
  return cv.b;
}

// ---------------------------------------------------------------------------
// prep_all (single launch): x convert + 4 weight transposes + Wa transpose
// ---------------------------------------------------------------------------
__global__ __launch_bounds__(256)
void prep_all(const float* __restrict__ x, u16* __restrict__ xb,
              const float* __restrict__ Wq, u16* __restrict__ WqT,
              const float* __restrict__ Wk, u16* __restrict__ WkT,
              const float* __restrict__ Wv, u16* __restrict__ WvT,
              const float* __restrict__ Wo, u16* __restrict__ WoT,
              const float* __restrict__ Wa, u16* __restrict__ WaT) {
  __shared__ float tile[32][33];
  const int bid = blockIdx.x;
  const int tid = threadIdx.x;
  if (bid < 8192) {
    size_t i = ((size_t)bid * 256 + tid) * 8;
    f32x4 a = *(const f32x4*)(x + i);
    f32x4 b = *(const f32x4*)(x + i + 4);
    u16x8 o;
    o[0] = f2bf(a[0]); o[1] = f2bf(a[1]); o[2] = f2bf(a[2]); o[3] = f2bf(a[3]);
    o[4] = f2bf(b[0]); o[5] = f2bf(b[1]); o[6] = f2bf(b[2]); o[7] = f2bf(b[3]);
    *(u16x8*)(xb + i) = o;
    return;
  }
  if (bid < 12288) {
    const int t = (bid - 8192) >> 10;
    const int sub = (bid - 8192) & 1023;
    const float* in = (t == 0) ? Wq : (t == 1) ? Wk : (t == 2) ? Wv : Wo;
    u16* out = (t == 0) ? WqT : (t == 1) ? WkT : (t == 2) ? WvT : WoT;
    const int bx = (sub & 31) * 32, by = (sub >> 5) * 32;
    const int tx = tid & 31, ty = tid >> 5;
    for (int i2 = ty; i2 < 32; i2 += 8)
      tile[i2][tx] = in[(size_t)(by + i2) * 1024 + bx + tx];
    __syncthreads();
    for (int i2 = ty; i2 < 32; i2 += 8)
      out[(size_t)(bx + i2) * 1024 + by + tx] = f2bf(tile[tx][i2]);
    return;
  }
  {
    int idx = (bid - 12288) * 256 + tid;
    WaT[idx] = f2bf(Wa[(idx & 1023) * 16 + (idx >> 10)]);
  }
}

// ---------------------------------------------------------------------------
// a_proj (MFMA skinny GEMM): abuf = sigmoid(xb @ Wa + ba + 2), M=16384 N=16
// ---------------------------------------------------------------------------
__global__ __launch_bounds__(256)
void a_proj(const u16* __restrict__ xb, const u16* __restrict__ WaT,
            const float* __restrict__ ba, float* __restrict__ abuf) {
  __shared__ __align__(16) u16 As[256 * 32];
  __shared__ __align__(16) u16 Bs[16 * 32];
  const int tid = threadIdx.x;
  const int brow = blockIdx.x * 256;
  const int l = tid & 63, wid = tid >> 6;
  const int la = l & 15, kb8 = (l >> 4) * 8;
  const int sr = tid >> 2, se = (tid & 3) * 8;

  f32x4 acc[4];
#pragma unroll
  for (int mi = 0; mi < 4; ++mi) acc[mi] = (f32x4){0.f, 0.f, 0.f, 0.f};

  for (int kt = 0; kt < 32; ++kt) {
    const int k0 = kt * 32;
    __syncthreads();
#pragma unroll
    for (int i = 0; i < 4; ++i)
      gl2lds16(xb + (size_t)(brow + i * 64 + sr) * DD + k0 + se,
               &As[i * 2048 + wid * 512]);
    if (wid == 0)
      gl2lds16(WaT + (size_t)(l >> 2) * DD + k0 + (l & 3) * 8, &Bs[0]);
    __syncthreads();
    union { u16x8 u; bf16x8 b; } cvb;
    cvb.u = *(const u16x8*)&Bs[la * 32 + kb8];
#pragma unroll
    for (int mi = 0; mi < 4; ++mi) {
      union { u16x8 u; bf16x8 b; } cva;
      cva.u = *(const u16x8*)&As[(wid * 64 + mi * 16 + la) * 32 + kb8];
      acc[mi] = __builtin_amdgcn_mfma_f32_16x16x32_bf16(cva.b, cvb.b, acc[mi], 0, 0, 0);
    }
  }
  const float bav = ba[la];
#pragma unroll
  for (int mi = 0; mi < 4; ++mi)
#pragma unroll
    for (int rr = 0; rr < 4; ++rr) {
      int row = brow + wid * 64 + mi * 16 + ((l >> 4) << 2) + rr;
      float t = acc[mi][rr] + bav + 2.0f;
      abuf[(size_t)row * HH + la] = 1.f / (1.f + __expf(-t));
    }
}

// ---------------------------------------------------------------------------
// bf16 MFMA GEMM, 4-phase counted-vmcnt schedule (r8 bug FIXED):
// 256x256 tile, BK=64, 8 waves, 128KiB dbuf.
// Staged halves defined by quadrant structure (wave-uniform needs):
//   A_mH = rows [H*64,H*64+64) u [128+H*64, 128+H*64+64)
//   B_nH = rows wc*64+H*32..+32 for wc=0..3
// Quadrant order (0,0),(0,1),(1,1),(1,0); stage order A_m0,B_n0,B_n1,A_m1.
// Cumulative needs: p0:{s1,s2} p1:+s3 p2:+s4 p3:none ->
//   vmcnt(4) at ends of p0,p1,p3 (6->4 outstanding completes oldest half);
//   none at p2. Last tile drains vmcnt(2)/vmcnt(0).
// ROUTE=1: fused QKV (N=3072) routed bf16 epilogue w/ elu+1 on q/k.
// ROUTE=0: f32 output.  NCT = col-tile count (N/256).
// ---------------------------------------------------------------------------
#define MMA_Q(MIH, NIH) \
  __builtin_amdgcn_s_setprio(1); \
  _Pragma("unroll") \
  for (int m2 = 0; m2 < 4; ++m2) \
    _Pragma("unroll") \
    for (int n2 = 0; n2 < 2; ++n2) \
      _Pragma("unroll") \
      for (int kk = 0; kk < 2; ++kk) \
        acc[(MIH) * 4 + m2][(NIH) * 2 + n2] = \
            __builtin_amdgcn_mfma_f32_16x16x32_bf16( \
                af[m2][kk], bfr[n2][kk], \
                acc[(MIH) * 4 + m2][(NIH) * 2 + n2], 0, 0, 0); \
  __builtin_amdgcn_s_setprio(0);

#define RD_A(LA, MIH) \
  _Pragma("unroll") \
  for (int m2 = 0; m2 < 4; ++m2) \
    _Pragma("unroll") \
    for (int kk = 0; kk < 2; ++kk) \
      af[m2][kk] = ldsw(LA, wr * 128 + (MIH) * 64 + m2 * 16 + la, kk * 32 + kb8);

#define RD_B(LB, NIH) \
  _Pragma("unroll") \
  for (int n2 = 0; n2 < 2; ++n2) \
    _Pragma("unroll") \
    for (int kk = 0; kk < 2; ++kk) \
      bfr[n2][kk] = ldsw(LB, wc * 64 + (NIH) * 32 + n2 * 16 + la, kk * 32 + kb8);

#define VMCNT(N) \
  asm volatile("s_waitcnt vmcnt(" #N ")" ::: "memory"); \
  __builtin_amdgcn_sched_barrier(0);

template<int NCT, int ROUTE>
__global__ __launch_bounds__(512)
void gemm_4p(const u16* __restrict__ A, const u16* __restrict__ Bt,
             void* __restrict__ Cout) {
  __shared__ __align__(16) u16 As[2][256 * 64];
  __shared__ __align__(16) u16 Bs[2][256 * 64];
  const int tid = threadIdx.x;
  const int nwg = gridDim.x;
  const int f = blockIdx.x;
  const int swz = (f & 7) * (nwg >> 3) + (f >> 3);
  const int brow = (swz / NCT) * 256;
  const int bcol = (swz % NCT) * 256;
  const int l = tid & 63;
  const int wid = tid >> 6;       // 0..7
  const int wr = wid >> 2;        // 0..1  (M half)
  const int wc = wid & 3;         // 0..3  (N quarter)
  const int la = l & 15, kb8 = (l >> 4) * 8;
  const int K = 1024;
  const int srow = l >> 3;                       // row within 8-row chunk
  const int scol = ((l & 7) * 8) ^ (srow << 3);  // pre-swizzled global col (u16)

  // stage one A-half (H): chunks H*8+{0..7} and 16+H*8+{0..7}; 2 per wave
  auto stageA = [&](int H, int koff, u16* dst) {
#pragma unroll
    for (int j = 0; j < 2; ++j) {
      const int i2 = wid * 2 + j;
      const int chunk = (i2 < 8) ? (H * 8 + i2) : (16 + H * 8 + (i2 - 8));
      gl2lds16(A + (size_t)(brow + chunk * 8 + srow) * K + koff + scol,
               dst + chunk * 512);
    }
  };
  // stage one B-half (H): chunks wcg*8 + H*4 + {0..3}
  auto stageB = [&](int H, int koff, u16* dst) {
#pragma unroll
    for (int j = 0; j < 2; ++j) {
      const int i2 = wid * 2 + j;
      const int chunk = (i2 >> 2) * 8 + H * 4 + (i2 & 3);
      gl2lds16(Bt + (size_t)(bcol + chunk * 8 + srow) * K + koff + scol,
               dst + chunk * 512);
    }
  };

  f32x4 acc[8][4];
#pragma unroll
  for (int i = 0; i < 8; ++i)
#pragma unroll
    for (int j = 0; j < 4; ++j) acc[i][j] = (f32x4){0.f, 0.f, 0.f, 0.f};

  // prologue: stage tile 0 in canonical order s1..s4
  stageA(0, 0, As[0]);
  stageB(0, 0, Bs[0]);
  stageB(1, 0, Bs[0]);
  stageA(1, 0, As[0]);
  VMCNT(4);                       // s1,s2 landed
  __builtin_amdgcn_s_barrier();

  const int NKT = K / 64;
  bf16x8 af[4][2], bfr[2][2];
  for (int kt = 0; kt < NKT; ++kt) {
    const u16* lA = As[kt & 1];
    const u16* lB = Bs[kt & 1];
    u16* nA = As[(kt + 1) & 1];
    u16* nB = Bs[(kt + 1) & 1];
    const int kn = (kt + 1) * 64;
    const bool more = (kt + 1 < NKT);

    // ---- p0: q(0,0); stage s1'=A_m0
    RD_A(lA, 0);
    RD_B(lB, 0);
    if (more) stageA(0, kn, nA);
    __builtin_amdgcn_s_barrier();
    MMA_Q(0, 0);
    if (more) { VMCNT(4); } else { VMCNT(2); }   // s3 (B_n1) landed
    __builtin_amdgcn_s_barrier();

    // ---- p1: q(0,1); stage s2'=B_n0
    RD_B(lB, 1);
    if (more) stageB(0, kn, nB);
    __builtin_amdgcn_s_barrier();
    MMA_Q(0, 1);
    if (more) { VMCNT(4); } else { VMCNT(0); }   // s4 (A_m1) landed
    __builtin_amdgcn_s_barrier();

    // ---- p2: q(1,1); stage s3'=B_n1; no wait needed
    RD_A(lA, 1);
    if (more) stageB(1, kn, nB);
    __builtin_amdgcn_s_barrier();
    MMA_Q(1, 1);
    __builtin_amdgcn_s_barrier();

    // ---- p3: q(1,0); stage s4'=A_m1
    RD_B(lB, 0);
    if (more) stageA(1, kn, nA);
    __builtin_amdgcn_s_barrier();
    MMA_Q(1, 0);
    if (more) { VMCNT(4); }                      // s1',s2' landed for next p0
    __builtin_amdgcn_s_barrier();
  }

  const int wrow = wr * 128, wcol = wc * 64;
  if (ROUTE) {
    u16* base = (u16*)Cout + (size_t)(bcol >> 10) * ((size_t)MM * 1024);
    const bool act = (bcol < 2048);
#pragma unroll
    for (int mi = 0; mi < 8; ++mi)
#pragma unroll
      for (int ni = 0; ni < 4; ++ni)
#pragma unroll
        for (int rr = 0; rr < 4; ++rr) {
          int row = brow + wrow + mi * 16 + ((l >> 4) << 2) + rr;
          int c2 = (bcol & 1023) + wcol + ni * 16 + la;
          float v = acc[mi][ni][rr];
          if (act) v = v > 0.f ? v + 1.f : __expf(v);
          base[(size_t)row * 1024 + c2] = f2bf(v);
        }
  } else {
#pragma unroll
    for (int mi = 0; mi < 8; ++mi)
#pragma unroll
      for (int ni = 0; ni < 4; ++ni)
#pragma unroll
        for (int rr = 0; rr < 4; ++rr) {
          int row = brow + wrow + mi * 16 + ((l >> 4) << 2) + rr;
          int col = bcol + wcol + ni * 16 + la;
          ((float*)Cout)[(size_t)row * 1024 + col] = acc[mi][ni][rr];
        }
  }
}

// ---------------------------------------------------------------------------
// FUSED Kernel A + scan level 1, cA-hoisted + k/v software pipeline.
// ---------------------------------------------------------------------------
__global__ __launch_bounds__(256)
void chunk_local_scan(const u16* __restrict__ kb, const u16* __restrict__ vb,
                      const float* __restrict__ abuf,
                      u16* __restrict__ Sbuf, float* __restrict__ zbuf,
                      float* __restrict__ cAbuf,
                      float* __restrict__ GAgg, float* __restrict__ zGAgg,
                      float* __restrict__ dpbuf) {
  const int g = blockIdx.x & (NGRP - 1);
  const int bh = blockIdx.x >> 4;
  const int h = bh & (HH - 1);
  const int b = bh >> 4;
  __shared__ __align__(16) u16 KT[64 * 64];
  __shared__ __align__(16) u16 VTl[64 * 64];
  __shared__ float wshA[GCH][64];
  __shared__ float dchA[GCH];
  const int tid = threadIdx.x;
  const int r = tid >> 2, e = (tid & 3) * 16;
  const int l = tid & 63, w = tid >> 6;
  const int kb8 = (l >> 4) << 3, la = l & 15;
  const int dw = 16 * w + ((l >> 4) << 2);
  const int dkz = tid >> 2, tqz = (tid & 3) * 16, swkz = (dkz & 7) << 3;
  const int c0 = g * GCH;
  const int rowbase0 = b * NNLEN + c0 * LCH;

  // hoisted cA prefix scans: wave w handles chunks 2w, 2w+1
#pragma unroll
  for (int ii = 0; ii < 2; ++ii) {
    const int i = w * 2 + ii;
    const int blkc = bh * CCHUNK + c0 + i;
    float v = __logf(abuf[(size_t)(rowbase0 + i * LCH + l) * HH + h]);
#pragma unroll
    for (int d = 1; d < 64; d <<= 1) {
      float u = __shfl_up(v, d);
      if (l >= d) v += u;
    }
    cAbuf[(size_t)blkc * 64 + l] = v;
    float tot = __shfl(v, 63);
    wshA[i][l] = __expf(tot - v);
    if (l == 0) dchA[i] = __expf(tot);
  }
  __syncthreads();
  if (tid == 0) {
    float rp = 1.f;
#pragma unroll
    for (int i = 0; i < GCH; ++i) {
      dpbuf[bh * CCHUNK + c0 + i] = rp;
      rp *= dchA[i];
    }
  }

  f32x4 run[4];
#pragma unroll
  for (int ni = 0; ni < 4; ++ni) run[ni] = (f32x4){0.f, 0.f, 0.f, 0.f};
  float zrun = 0.f;

  const u16* kp = kb + (size_t)(rowbase0 + r) * PP + h * DH + e;
  const u16* vp = vb + (size_t)(rowbase0 + r) * PP + h * DH + e;
  u16x8 k0 = *(const u16x8*)kp, k1 = *(const u16x8*)(kp + 8);
  u16x8 v0 = *(const u16x8*)vp, v1 = *(const u16x8*)(vp + 8);

  for (int i = 0; i < GCH; ++i) {
    const int blkc = bh * CCHUNK + c0 + i;
    if (i) __syncthreads();

    {
      const float wt = wshA[i][r];
#pragma unroll
      for (int j = 0; j < 8; ++j) {
        int d0 = e + j, d1 = e + 8 + j;
        KT[d0 * 64 + (r ^ ((d0 & 7) << 3))] = f2bf(bf2f(k0[j]) * wt);
        KT[d1 * 64 + (r ^ ((d1 & 7) << 3))] = f2bf(bf2f(k1[j]) * wt);
        VTl[d0 * 64 + (r ^ ((d0 & 7) << 3))] = v0[j];
        VTl[d1 * 64 + (r ^ ((d1 & 7) << 3))] = v1[j];
      }
    }
    __syncthreads();

    if (i + 1 < GCH) {
      const int rb = rowbase0 + (i + 1) * LCH;
      kp = kb + (size_t)(rb + r) * PP + h * DH + e;
      vp = vb + (size_t)(rb + r) * PP + h * DH + e;
      k0 = *(const u16x8*)kp; k1 = *(const u16x8*)(kp + 8);
      v0 = *(const u16x8*)vp; v1 = *(const u16x8*)(vp + 8);
    }

    const float dch = dchA[i];
    f32x4 s[4];
#pragma unroll
    for (int ni = 0; ni < 4; ++ni) s[ni] = (f32x4){0.f, 0.f, 0.f, 0.f};
#pragma unroll
    for (int kk = 0; kk < 2; ++kk) {
      bf16x8 av = ldsw(VTl, 16 * w + la, kk * 32 + kb8);
#pragma unroll
      for (int ni = 0; ni < 4; ++ni)
        s[ni] = __builtin_amdgcn_mfma_f32_16x16x32_bf16(
            av, ldsw(KT, 16 * ni + la, kk * 32 + kb8), s[ni], 0, 0, 0);
    }

    u16* Sc = Sbuf + (size_t)blkc * 4096;
#pragma unroll
    for (int ni = 0; ni < 4; ++ni)
#pragma unroll
      for (int rr = 0; rr < 4; ++rr)
        Sc[(dw + rr) * 64 + 16 * ni + la] = f2bf(run[ni][rr]);
#pragma unroll
    for (int ni = 0; ni < 4; ++ni)
#pragma unroll
      for (int rr = 0; rr < 4; ++rr)
        run[ni][rr] = dch * run[ni][rr] + s[ni][rr];

    {
      float zp = 0.f;
#pragma unroll
      for (int i2 = 0; i2 < 16; ++i2)
        zp += bf2f(KT[dkz * 64 + ((tqz + i2) ^ swkz)]);
      zp += __shfl_xor(zp, 1);
      zp += __shfl_xor(zp, 2);
      if ((tid & 3) == 0) zbuf[(size_t)blkc * 64 + dkz] = zrun;
      zrun = dch * zrun + zp;
    }
  }

  float* Ga = GAgg + ((size_t)bh * NGRP + g) * 4096;
#pragma unroll
  for (int ni = 0; ni < 4; ++ni)
#pragma unroll
    for (int rr = 0; rr < 4; ++rr)
      Ga[(dw + rr) * 64 + 16 * ni + la] = run[ni][rr];
  if ((tid & 3) == 0)
    zGAgg[((size_t)bh * NGRP + g) * 64 + dkz] = zrun;
}

// ---------------------------------------------------------------------------
// Scan level 2: across the 16 group aggregates. GAgg(f32) -> GBeg (bf16).
// ---------------------------------------------------------------------------
__global__ __launch_bounds__(1024)
void scan_top(const float* __restrict__ GAgg, u16* __restrict__ GBeg,
              float* __restrict__ zGAgg, const float* __restrict__ cAbuf) {
  const int bh = blockIdx.x;
  const size_t cb = (size_t)bh * CCHUNK;
  __shared__ float Dsh[NGRP];
  if (threadIdx.x < NGRP) {
    float s = 0.f;
#pragma unroll
    for (int i = 0; i < GCH; ++i)
      s += cAbuf[(cb + threadIdx.x * GCH + i) * 64 + 63];
    Dsh[threadIdx.x] = __expf(s);
  }
  __syncthreads();
  const int elem = threadIdx.x * 4;
  const float* base = GAgg + (size_t)bh * NGRP * 4096;
  u16* gb = GBeg + (size_t)bh * NGRP * 4096;
  f32x4 run = (f32x4){0.f, 0.f, 0.f, 0.f};
  f32x4 cur = *(const f32x4*)&base[elem];
#pragma unroll
  for (int gg = 0; gg < NGRP; ++gg) {
    f32x4 nxt;
    if (gg + 1 < NGRP) nxt = *(const f32x4*)&base[(gg + 1) * 4096 + elem];
    u16x4 o;
#pragma unroll
    for (int jj = 0; jj < 4; ++jj) o[jj] = f2bf(run[jj]);
    *(u16x4*)&gb[gg * 4096 + elem] = o;
    const float D = Dsh[gg];
#pragma unroll
    for (int jj = 0; jj < 4; ++jj) run[jj] = D * run[jj] + cur[jj];
    cur = nxt;
  }
  if (threadIdx.x < 64) {
    float* zb = zGAgg + (size_t)bh * NGRP * 64;
    float zr = 0.f;
#pragma unroll
    for (int gg = 0; gg < NGRP; ++gg) {
      float a = zb[gg * 64 + threadIdx.x];
      zb[gg * 64 + threadIdx.x] = zr;
      zr = Dsh[gg] * zr + a;
    }
  }
}

// ---------------------------------------------------------------------------
// Kernel C (MFMA): per-chunk output.
// ---------------------------------------------------------------------------
__global__ __launch_bounds__(256)
void chunk_out(u16* __restrict__ qb, const u16* __restrict__ kb,
               const u16* __restrict__ vb, const u16* __restrict__ Sbuf,
               const float* __restrict__ zbuf, const float* __restrict__ cAbuf,
               const u16* __restrict__ GBeg, const float* __restrict__ zGAgg,
               const float* __restrict__ dpbuf) {
  const int blk = blockIdx.x;
  const int c = blk & (CCHUNK - 1);
  const int h = (blk >> 7) & (HH - 1);
  const int b = blk >> 11;
  const int bh = blk >> 7;
  const int g = c >> 3;
  const int rowbase = b * NNLEN + c * LCH;

  __shared__ __align__(16) u16 Qs[64 * 64];
  __shared__ __align__(16) u16 Ke[64 * 64];   // Ke, later reused as P tile
  __shared__ __align__(16) u16 VT[64 * 64];
  __shared__ __align__(16) u16 STs[64 * 64];
  __shared__ float cAsh[64], zsh[64], denP[64], qzs[64];

  const int tid = threadIdx.x;
  const int r = tid >> 2, e = (tid & 3) * 16;
  const float dp = dpbuf[blk];

  const u16* qp = qb + (size_t)(rowbase + r) * PP + h * DH + e;
  const u16* kp = kb + (size_t)(rowbase + r) * PP + h * DH + e;
  const u16* vp = vb + (size_t)(rowbase + r) * PP + h * DH + e;
  u16x8 q0 = *(const u16x8*)qp, q1 = *(const u16x8*)(qp + 8);
  u16x8 k0 = *(const u16x8*)kp, k1 = *(const u16x8*)(kp + 8);
  u16x8 v0 = *(const u16x8*)vp, v1 = *(const u16x8*)(vp + 8);
  const u16* sp = Sbuf + (size_t)blk * 4096 + r * 64 + e;
  u16x8 p0 = *(const u16x8*)sp, p1 = *(const u16x8*)(sp + 8);
  const u16* gp = GBeg + ((size_t)bh * NGRP + g) * 4096 + r * 64 + e;
  u16x8 gb0 = *(const u16x8*)gp, gb1 = *(const u16x8*)(gp + 8);
  if (tid < 64) {
    cAsh[tid] = cAbuf[(size_t)blk * 64 + tid];
    zsh[tid] = zbuf[(size_t)blk * 64 + tid]
             + dp * zGAgg[((size_t)bh * NGRP + g) * 64 + tid];
  }
  __syncthreads();

  {
    const float c0c = cAsh[31];
    const int sw = (r & 7) << 3;
    const float qsc = __expf(cAsh[r] - c0c);
    const float ksc = __expf(c0c - cAsh[r]);
    const float ssc = __expf(c0c);
    u16x8 t0, t1, u0, u1, w0, w1;
#pragma unroll
    for (int j = 0; j < 8; ++j) {
      t0[j] = f2bf(bf2f(q0[j]) * qsc);
      t1[j] = f2bf(bf2f(q1[j]) * qsc);
      u0[j] = f2bf(bf2f(k0[j]) * ksc);
      u1[j] = f2bf(bf2f(k1[j]) * ksc);
    }
#pragma unroll
    for (int j = 0; j < 8; ++j) {
      w0[j] = f2bf((bf2f(p0[j]) + dp * bf2f(gb0[j])) * ssc);
      w1[j] = f2bf((bf2f(p1[j]) + dp * bf2f(gb1[j])) * ssc);
    }
    *(u16x8*)&Qs[r * 64 + (e ^ sw)] = t0;
    *(u16x8*)&Qs[r * 64 + ((e + 8) ^ sw)] = t1;
    *(u16x8*)&Ke[r * 64 + (e ^ sw)] = u0;
    *(u16x8*)&Ke[r * 64 + ((e + 8) ^ sw)] = u1;
    *(u16x8*)&STs[r * 64 + (e ^ sw)] = w0;
    *(u16x8*)&STs[r * 64 + ((e + 8) ^ sw)] = w1;
#pragma unroll
    for (int j = 0; j < 8; ++j) {
      int d0 = e + j, d1 = e + 8 + j;
      VT[d0 * 64 + (r ^ ((d0 & 7) << 3))] = v0[j];
      VT[d1 * 64 + (r ^ ((d1 & 7) << 3))] = v1[j];
    }
    if (tid < 64) zsh[tid] *= ssc;
  }
  __syncthreads();

  const int l = tid & 63, w = tid >> 6;
  const int kb8 = (l >> 4) << 3, la = l & 15;

  // --- MFMA1: P = Qe @ Ke^T ---
  bf16x8 aq[2];
  f32x4 p[4];
#pragma unroll
  for (int ni = 0; ni < 4; ++ni) p[ni] = (f32x4){0.f, 0.f, 0.f, 0.f};
#pragma unroll
  for (int kk = 0; kk < 2; ++kk) {
    aq[kk] = ldsw(Qs, 16 * w + la, kk * 32 + kb8);
#pragma unroll
    for (int ni = 0; ni < 4; ++ni)
      p[ni] = __builtin_amdgcn_mfma_f32_16x16x32_bf16(
          aq[kk], ldsw(Ke, 16 * ni + la, kk * 32 + kb8), p[ni], 0, 0, 0);
  }

  const int tw = 16 * w + ((l >> 4) << 2);
  float rsum[4] = {0.f, 0.f, 0.f, 0.f};
#pragma unroll
  for (int ni = 0; ni < 4; ++ni)
#pragma unroll
    for (int rr = 0; rr < 4; ++rr) {
      int s = 16 * ni + la, t = tw + rr;
      float v = (s <= t) ? p[ni][rr] : 0.f;
      p[ni][rr] = v;
      rsum[rr] += v;
    }
#pragma unroll
  for (int d = 1; d < 16; d <<= 1)
#pragma unroll
    for (int rr = 0; rr < 4; ++rr) rsum[rr] += __shfl_xor(rsum[rr], d);
  if (la == 0)
#pragma unroll
    for (int rr = 0; rr < 4; ++rr) denP[tw + rr] = rsum[rr];

  // qz[row] = Qe[row] . z0e from register fragments
  {
    float qzp = 0.f;
#pragma unroll
    for (int kk = 0; kk < 2; ++kk)
#pragma unroll
      for (int j = 0; j < 8; ++j) {
        union { bf16x8 b; u16x8 u; } cv; cv.b = aq[kk];
        qzp += bf2f(cv.u[j]) * zsh[kk * 32 + kb8 + j];
      }
    qzp += __shfl_xor(qzp, 16);
    qzp += __shfl_xor(qzp, 32);
    if (l < 16) qzs[16 * w + la] = qzp;
  }
  __syncthreads();

  // write P into (dead) Ke tile, swizzled
#pragma unroll
  for (int ni = 0; ni < 4; ++ni)
#pragma unroll
    for (int rr = 0; rr < 4; ++rr) {
      int t = tw + rr, s = 16 * ni + la;
      Ke[t * 64 + (s ^ ((t & 7) << 3))] = f2bf(p[ni][rr]);
    }
  __syncthreads();

  // --- MFMA2: O = P@V + Qe@S0e^T ---
  f32x4 o[4];
#pragma unroll
  for (int ni = 0; ni < 4; ++ni) o[ni] = (f32x4){0.f, 0.f, 0.f, 0.f};
#pragma unroll
  for (int kk = 0; kk < 2; ++kk) {
    bf16x8 ap = ldsw(Ke, 16 * w + la, kk * 32 + kb8);
#pragma unroll
    for (int ni = 0; ni < 4; ++ni)
      o[ni] = __builtin_amdgcn_mfma_f32_16x16x32_bf16(
          ap, ldsw(VT, 16 * ni + la, kk * 32 + kb8), o[ni], 0, 0, 0);
  }
#pragma unroll
  for (int kk = 0; kk < 2; ++kk)
#pragma unroll
    for (int ni = 0; ni < 4; ++ni)
      o[ni] = __builtin_amdgcn_mfma_f32_16x16x32_bf16(
          aq[kk], ldsw(STs, 16 * ni + la, kk * 32 + kb8), o[ni], 0, 0, 0);

  float dn[4];
#pragma unroll
  for (int rr = 0; rr < 4; ++rr) dn[rr] = qzs[tw + rr] + denP[tw + rr] + EPSV;
#pragma unroll
  for (int ni = 0; ni < 4; ++ni)
#pragma unroll
    for (int rr = 0; rr < 4; ++rr) {
      int t = tw + rr, dv = 16 * ni + la;
      qb[(size_t)(rowbase + t) * PP + h * DH + dv] = f2bf(o[ni][rr] / dn[rr]);
    }
}

// ---------------------------------------------------------------------------
extern "C" void kernel_launch(void* const* d_in, const int* in_sizes, int n_in,
                              void* d_out, int out_size, void* d_ws, size_t ws_size,
                              hipStream_t stream) {
  const float* x  = (const float*)d_in[0];
  const float* Wq = (const float*)d_in[1];
  const float* Wk = (const float*)d_in[2];
  const float* Wv = (const float*)d_in[3];
  const float* Wo = (const float*)d_in[4];
  const float* Wa = (const float*)d_in[5];
  const float* ba = (const float*)d_in[6];

  char* ws = (char*)d_ws;
  size_t off = 0;
  auto carve = [&](size_t bytes) {
    void* p = ws + off;
    off += (bytes + 255) & ~(size_t)255;
    return p;
  };
  u16* xb   = (u16*)carve((size_t)MM * DD * 2);
  u16* WqT  = (u16*)carve((size_t)PP * DD * 2);  // WqT/WkT/WvT contiguous
  u16* WkT  = (u16*)carve((size_t)PP * DD * 2);
  u16* WvT  = (u16*)carve((size_t)PP * DD * 2);
  u16* WoT  = (u16*)carve((size_t)DD * PP * 2);
  u16* WaT  = (u16*)carve((size_t)HH * DD * 2);
  u16* qb   = (u16*)carve((size_t)MM * PP * 2);  // qb/kb/vb contiguous
  u16* kb   = (u16*)carve((size_t)MM * PP * 2);
  u16* vb   = (u16*)carve((size_t)MM * PP * 2);
  float* abuf  = (float*)carve((size_t)MM * HH * 4);
  u16*  Sbuf   = (u16*)carve((size_t)BBATCH * HH * CCHUNK * 4096 * 2);
  float* zbuf  = (float*)carve((size_t)BBATCH * HH * CCHUNK * 64 * 4);
  float* cAbuf = (float*)carve((size_t)BBATCH * HH * CCHUNK * 64 * 4);
  float* GAgg  = (float*)carve((size_t)BBATCH * HH * NGRP * 4096 * 4);
  u16*  GBeg   = (u16*)carve((size_t)BBATCH * HH * NGRP * 4096 * 2);
  float* zGAgg = (float*)carve((size_t)BBATCH * HH * NGRP * 64 * 4);
  float* dpbuf = (float*)carve((size_t)BBATCH * HH * CCHUNK * 4);

  prep_all<<<12352, 256, 0, stream>>>(x, xb, Wq, WqT, Wk, WkT, Wv, WvT,
                                      Wo, WoT, Wa, WaT);
  a_proj<<<MM / 256, 256, 0, stream>>>(xb, WaT, ba, abuf);

  // fused QKV: M=16384, N=3072 (WqT/WkT/WvT contiguous), routed epilogue
  gemm_4p<12, 1><<<(MM / 256) * 12, 512, 0, stream>>>(xb, WqT, qb);

  chunk_local_scan<<<BBATCH * HH * NGRP, 256, 0, stream>>>(
      kb, vb, abuf, Sbuf, zbuf, cAbuf, GAgg, zGAgg, dpbuf);
  scan_top<<<BBATCH * HH, 1024, 0, stream>>>(GAgg, GBeg, zGAgg, cAbuf);
  chunk_out<<<BBATCH * HH * CCHUNK, 256, 0, stream>>>(qb, kb, vb, Sbuf, zbuf, cAbuf,
                                                      GBeg, zGAgg, dpbuf);

  gemm_4p<4, 0><<<(MM / 256) * 4, 512, 0, stream>>>(qb, WoT, (float*)d_out);
}

// Round 12
// 246.352 us; speedup vs baseline: 1.0747x; 1.0491x over previous
//
#include <hip/hip_runtime.h>
#include <stdint.h>

#define HH 16
#define DH 64
#define DD 1024
#define PP 1024
#define NNLEN 8192
#define BBATCH 2
#define MM (BBATCH*NNLEN)   // 16384 rows
#define CCHUNK 128          // chunks per (b,h)
#define LCH 64              // chunk length
#define NGRP 16             // scan groups per (b,h)
#define GCH 8               // chunks per group
#define EPSV 1e-6f

typedef unsigned short u16;
typedef __attribute__((ext_vector_type(4))) unsigned short u16x4;
typedef __attribute__((ext_vector_type(8))) unsigned short u16x8;
typedef __attribute__((ext_vector_type(8))) __bf16 bf16x8;
typedef __attribute__((ext_vector_type(4))) float f32x4;

__device__ __forceinline__ u16 f2bf(float f) {
  unsigned x = __float_as_uint(f);
  return (u16)((x + 0x7fffu + ((x >> 16) & 1u)) >> 16);
}
__device__ __forceinline__ float bf2f(u16 u) {
  return __uint_as_float(((unsigned)u) << 16);
}

// async global->LDS, 16B per lane. LDS dest must be wave-uniform base.
__device__ __forceinline__ void gl2lds16(const void* g, void* l) {
  __builtin_amdgcn_global_load_lds(
      reinterpret_cast<__attribute__((address_space(1))) void*>(
          reinterpret_cast<uintptr_t>(g)),
      reinterpret_cast<__attribute__((address_space(3))) void*>(
          reinterpret_cast<uintptr_t>(l)),
      16, 0, 0);
}

// swizzled LDS read of a bf16x8 fragment from a [*][64] u16 tile.
__device__ __forceinline__ bf16x8 ldsw(const u16* base, int row, int col) {
  union { u16x8 u; bf16x8 b; } cv;
  cv.u = *(const u16x8*)&base[row * 64 + (col ^ ((row & 7) << 3))];
  return cv.b;
}

// ---------------------------------------------------------------------------
// prep_all (single launch): x convert + 4 weight transposes + Wa transpose
// ---------------------------------------------------------------------------
__global__ __launch_bounds__(256)
void prep_all(const float* __restrict__ x, u16* __restrict__ xb,
              const float* __restrict__ Wq, u16* __restrict__ WqT,
              const float* __restrict__ Wk, u16* __restrict__ WkT,
              const float* __restrict__ Wv, u16* __restrict__ WvT,
              const float* __restrict__ Wo, u16* __restrict__ WoT,
              const float* __restrict__ Wa, u16* __restrict__ WaT) {
  __shared__ float tile[32][33];
  const int bid = blockIdx.x;
  const int tid = threadIdx.x;
  if (bid < 8192) {
    size_t i = ((size_t)bid * 256 + tid) * 8;
    f32x4 a = *(const f32x4*)(x + i);
    f32x4 b = *(const f32x4*)(x + i + 4);
    u16x8 o;
    o[0] = f2bf(a[0]); o[1] = f2bf(a[1]); o[2] = f2bf(a[2]); o[3] = f2bf(a[3]);
    o[4] = f2bf(b[0]); o[5] = f2bf(b[1]); o[6] = f2bf(b[2]); o[7] = f2bf(b[3]);
    *(u16x8*)(xb + i) = o;
    return;
  }
  if (bid < 12288) {
    const int t = (bid - 8192) >> 10;
    const int sub = (bid - 8192) & 1023;
    const float* in = (t == 0) ? Wq : (t == 1) ? Wk : (t == 2) ? Wv : Wo;
    u16* out = (t == 0) ? WqT : (t == 1) ? WkT : (t == 2) ? WvT : WoT;
    const int bx = (sub & 31) * 32, by = (sub >> 5) * 32;
    const int tx = tid & 31, ty = tid >> 5;
    for (int i2 = ty; i2 < 32; i2 += 8)
      tile[i2][tx] = in[(size_t)(by + i2) * 1024 + bx + tx];
    __syncthreads();
    for (int i2 = ty; i2 < 32; i2 += 8)
      out[(size_t)(bx + i2) * 1024 + by + tx] = f2bf(tile[tx][i2]);
    return;
  }
  {
    int idx = (bid - 12288) * 256 + tid;
    WaT[idx] = f2bf(Wa[(idx & 1023) * 16 + (idx >> 10)]);
  }
}

// ---------------------------------------------------------------------------
// bf16 MFMA GEMM, minimal-barrier double-buffer, STAGE-FIRST (r9-verified):
// 256x256 tile, BK=64, 8 waves, ONE vmcnt(0)+s_barrier per K-tile.
// Col-major-within-XCD tile ordering: each XCD's R=8 consecutive blocks
// share one B col-panel (512KB, L2-resident) before switching columns.
// ROUTE=1: fused QKV (N=3072, NGT=768) + 64 tail blocks running a 512-thread
//          a_proj (abuf = sigmoid(xb@Wa + ba + 2)), reusing the GEMM LDS.
// ROUTE=0: f32 output (Wo).  NCT = col tiles, NGT = gemm block count.
// ---------------------------------------------------------------------------
template<int NCT, int NGT, int ROUTE>
__global__ __launch_bounds__(512)
void gemm_db(const u16* __restrict__ A, const u16* __restrict__ Bt,
             void* __restrict__ Cout, const u16* __restrict__ WaT,
             const float* __restrict__ ba, float* __restrict__ abuf) {
  __shared__ __align__(16) u16 As[2][256 * 64];
  __shared__ __align__(16) u16 Bs[2][256 * 64];
  const int tid = threadIdx.x;
  const int f = blockIdx.x;
  const int l = tid & 63;
  const int wid = tid >> 6;       // 0..7
  const int la = l & 15, kb8 = (l >> 4) * 8;
  const int K = 1024;

  if (ROUTE && f >= NGT) {
    // ---- fused a_proj: 256 rows per block, 8 waves, BK=32 ----
    const int brow2 = (f - NGT) * 256;
    const int sr = tid >> 2, se = (tid & 3) * 8;
    u16* As0 = As[0];
    u16* Bs0 = Bs[0];
    f32x4 acc2[2];
    acc2[0] = (f32x4){0.f, 0.f, 0.f, 0.f};
    acc2[1] = (f32x4){0.f, 0.f, 0.f, 0.f};
    for (int kt = 0; kt < 32; ++kt) {
      const int k0 = kt * 32;
      __syncthreads();
      gl2lds16(A + (size_t)(brow2 + sr) * DD + k0 + se, &As0[wid * 512]);
      gl2lds16(A + (size_t)(brow2 + 128 + sr) * DD + k0 + se,
               &As0[4096 + wid * 512]);
      if (wid == 0)
        gl2lds16(WaT + (size_t)(l >> 2) * DD + k0 + (l & 3) * 8, &Bs0[0]);
      __syncthreads();
      union { u16x8 u; bf16x8 b; } cvb;
      cvb.u = *(const u16x8*)&Bs0[la * 32 + kb8];
#pragma unroll
      for (int mi = 0; mi < 2; ++mi) {
        union { u16x8 u; bf16x8 b; } cva;
        cva.u = *(const u16x8*)&As0[(wid * 32 + mi * 16 + la) * 32 + kb8];
        acc2[mi] = __builtin_amdgcn_mfma_f32_16x16x32_bf16(cva.b, cvb.b, acc2[mi], 0, 0, 0);
      }
    }
    const float bav = ba[la];
#pragma unroll
    for (int mi = 0; mi < 2; ++mi)
#pragma unroll
      for (int rr = 0; rr < 4; ++rr) {
        int row = brow2 + wid * 32 + mi * 16 + ((l >> 4) << 2) + rr;
        float t = acc2[mi][rr] + bav + 2.0f;
        abuf[(size_t)row * HH + la] = 1.f / (1.f + __expf(-t));
      }
    return;
  }

  // col-major-within-XCD ordering
  const int C = NGT >> 3;        // tiles per XCD
  const int R = C / NCT;         // row-tiles per XCD (=8)
  const int xcd = f & 7, loc = f >> 3;
  const int brow = (xcd * R + loc % R) * 256;
  const int bcol = (loc / R) * 256;
  const int wr = wid >> 2;        // 0..1  (M half)
  const int wc = wid & 3;         // 0..3  (N quarter)
  const int srow = l >> 3;                       // row within 8-row chunk
  const int scol = ((l & 7) * 8) ^ (srow << 3);  // pre-swizzled global col
  const int ldso = (wid * 2) * 512;              // wave chunk base within half

  f32x4 acc[8][4];
#pragma unroll
  for (int i = 0; i < 8; ++i)
#pragma unroll
    for (int j = 0; j < 4; ++j) acc[i][j] = (f32x4){0.f, 0.f, 0.f, 0.f};

  // prologue: stage K-tile 0 into buf 0
#pragma unroll
  for (int h = 0; h < 2; ++h)
#pragma unroll
    for (int j = 0; j < 2; ++j) {
      const int r0 = h * 128 + (wid * 2 + j) * 8 + srow;
      gl2lds16(A  + (size_t)(brow + r0) * K + scol, &As[0][h * 8192 + ldso + j * 512]);
      gl2lds16(Bt + (size_t)(bcol + r0) * K + scol, &Bs[0][h * 8192 + ldso + j * 512]);
    }
  asm volatile("s_waitcnt vmcnt(0)" ::: "memory");
  __builtin_amdgcn_s_barrier();

  const int NKT = K / 64;
  for (int kt = 0; kt < NKT; ++kt) {
    const u16* lA = As[kt & 1];
    const u16* lB = Bs[kt & 1];
    u16* nA = As[(kt + 1) & 1];
    u16* nB = Bs[(kt + 1) & 1];
    const int knext = (kt + 1) * 64;
    const bool more = (kt + 1 < NKT);

    // stage next K-tile FIRST: the whole tile's compute covers the latency.
    if (more) {
#pragma unroll
      for (int h = 0; h < 2; ++h)
#pragma unroll
        for (int j = 0; j < 2; ++j) {
          const int r0 = h * 128 + (wid * 2 + j) * 8 + srow;
          gl2lds16(A  + (size_t)(brow + r0) * K + knext + scol,
                   nA + h * 8192 + ldso + j * 512);
          gl2lds16(Bt + (size_t)(bcol + r0) * K + knext + scol,
                   nB + h * 8192 + ldso + j * 512);
        }
    }

    bf16x8 af[4][2], bfr[4][2];
#pragma unroll
    for (int m2 = 0; m2 < 4; ++m2)
#pragma unroll
      for (int kk = 0; kk < 2; ++kk)
        af[m2][kk] = ldsw(lA, wr * 128 + m2 * 16 + la, kk * 32 + kb8);
#pragma unroll
    for (int n2 = 0; n2 < 4; ++n2)
#pragma unroll
      for (int kk = 0; kk < 2; ++kk)
        bfr[n2][kk] = ldsw(lB, wc * 64 + n2 * 16 + la, kk * 32 + kb8);

    __builtin_amdgcn_s_setprio(1);
#pragma unroll
    for (int m2 = 0; m2 < 4; ++m2)
#pragma unroll
      for (int n2 = 0; n2 < 4; ++n2)
#pragma unroll
        for (int kk = 0; kk < 2; ++kk)
          acc[m2][n2] = __builtin_amdgcn_mfma_f32_16x16x32_bf16(
              af[m2][kk], bfr[n2][kk], acc[m2][n2], 0, 0, 0);
    __builtin_amdgcn_s_setprio(0);

    // fragments: M-half 1 (reuse af regs; bfr persists)
#pragma unroll
    for (int m2 = 0; m2 < 4; ++m2)
#pragma unroll
      for (int kk = 0; kk < 2; ++kk)
        af[m2][kk] = ldsw(lA, wr * 128 + 64 + m2 * 16 + la, kk * 32 + kb8);

    __builtin_amdgcn_s_setprio(1);
#pragma unroll
    for (int m2 = 0; m2 < 4; ++m2)
#pragma unroll
      for (int n2 = 0; n2 < 4; ++n2)
#pragma unroll
        for (int kk = 0; kk < 2; ++kk)
          acc[4 + m2][n2] = __builtin_amdgcn_mfma_f32_16x16x32_bf16(
              af[m2][kk], bfr[n2][kk], acc[4 + m2][n2], 0, 0, 0);
    __builtin_amdgcn_s_setprio(0);

    if (more) {
      asm volatile("s_waitcnt vmcnt(0)" ::: "memory");
      __builtin_amdgcn_s_barrier();
    }
  }

  const int wrow = wr * 128, wcol = wc * 64;
  if (ROUTE) {
    u16* base = (u16*)Cout + (size_t)(bcol >> 10) * ((size_t)MM * 1024);
    const bool act = (bcol < 2048);
#pragma unroll
    for (int mi = 0; mi < 8; ++mi)
#pragma unroll
      for (int ni = 0; ni < 4; ++ni)
#pragma unroll
        for (int rr = 0; rr < 4; ++rr) {
          int row = brow + wrow + mi * 16 + ((l >> 4) << 2) + rr;
          int c2 = (bcol & 1023) + wcol + ni * 16 + la;
          float v = acc[mi][ni][rr];
          if (act) v = v > 0.f ? v + 1.f : __expf(v);
          base[(size_t)row * 1024 + c2] = f2bf(v);
        }
  } else {
#pragma unroll
    for (int mi = 0; mi < 8; ++mi)
#pragma unroll
      for (int ni = 0; ni < 4; ++ni)
#pragma unroll
        for (int rr = 0; rr < 4; ++rr) {
          int row = brow + wrow + mi * 16 + ((l >> 4) << 2) + rr;
          int col = bcol + wcol + ni * 16 + la;
          ((float*)Cout)[(size_t)row * 1024 + col] = acc[mi][ni][rr];
        }
  }
}

// ---------------------------------------------------------------------------
// FUSED Kernel A + scan level 1, cA-hoisted + k/v software pipeline.
// ---------------------------------------------------------------------------
__global__ __launch_bounds__(256)
void chunk_local_scan(const u16* __restrict__ kb, const u16* __restrict__ vb,
                      const float* __restrict__ abuf,
                      u16* __restrict__ Sbuf, float* __restrict__ zbuf,
                      float* __restrict__ cAbuf,
                      float* __restrict__ GAgg, float* __restrict__ zGAgg,
                      float* __restrict__ dpbuf) {
  const int g = blockIdx.x & (NGRP - 1);
  const int bh = blockIdx.x >> 4;
  const int h = bh & (HH - 1);
  const int b = bh >> 4;
  __shared__ __align__(16) u16 KT[64 * 64];
  __shared__ __align__(16) u16 VTl[64 * 64];
  __shared__ float wshA[GCH][64];
  __shared__ float dchA[GCH];
  const int tid = threadIdx.x;
  const int r = tid >> 2, e = (tid & 3) * 16;
  const int l = tid & 63, w = tid >> 6;
  const int kb8 = (l >> 4) << 3, la = l & 15;
  const int dw = 16 * w + ((l >> 4) << 2);
  const int dkz = tid >> 2, tqz = (tid & 3) * 16, swkz = (dkz & 7) << 3;
  const int c0 = g * GCH;
  const int rowbase0 = b * NNLEN + c0 * LCH;

#pragma unroll
  for (int ii = 0; ii < 2; ++ii) {
    const int i = w * 2 + ii;
    const int blkc = bh * CCHUNK + c0 + i;
    float v = __logf(abuf[(size_t)(rowbase0 + i * LCH + l) * HH + h]);
#pragma unroll
    for (int d = 1; d < 64; d <<= 1) {
      float u = __shfl_up(v, d);
      if (l >= d) v += u;
    }
    cAbuf[(size_t)blkc * 64 + l] = v;
    float tot = __shfl(v, 63);
    wshA[i][l] = __expf(tot - v);
    if (l == 0) dchA[i] = __expf(tot);
  }
  __syncthreads();
  if (tid == 0) {
    float rp = 1.f;
#pragma unroll
    for (int i = 0; i < GCH; ++i) {
      dpbuf[bh * CCHUNK + c0 + i] = rp;
      rp *= dchA[i];
    }
  }

  f32x4 run[4];
#pragma unroll
  for (int ni = 0; ni < 4; ++ni) run[ni] = (f32x4){0.f, 0.f, 0.f, 0.f};
  float zrun = 0.f;

  const u16* kp = kb + (size_t)(rowbase0 + r) * PP + h * DH + e;
  const u16* vp = vb + (size_t)(rowbase0 + r) * PP + h * DH + e;
  u16x8 k0 = *(const u16x8*)kp, k1 = *(const u16x8*)(kp + 8);
  u16x8 v0 = *(const u16x8*)vp, v1 = *(const u16x8*)(vp + 8);

  for (int i = 0; i < GCH; ++i) {
    const int blkc = bh * CCHUNK + c0 + i;
    if (i) __syncthreads();

    {
      const float wt = wshA[i][r];
#pragma unroll
      for (int j = 0; j < 8; ++j) {
        int d0 = e + j, d1 = e + 8 + j;
        KT[d0 * 64 + (r ^ ((d0 & 7) << 3))] = f2bf(bf2f(k0[j]) * wt);
        KT[d1 * 64 + (r ^ ((d1 & 7) << 3))] = f2bf(bf2f(k1[j]) * wt);
        VTl[d0 * 64 + (r ^ ((d0 & 7) << 3))] = v0[j];
        VTl[d1 * 64 + (r ^ ((d1 & 7) << 3))] = v1[j];
      }
    }
    __syncthreads();

    if (i + 1 < GCH) {
      const int rb = rowbase0 + (i + 1) * LCH;
      kp = kb + (size_t)(rb + r) * PP + h * DH + e;
      vp = vb + (size_t)(rb + r) * PP + h * DH + e;
      k0 = *(const u16x8*)kp; k1 = *(const u16x8*)(kp + 8);
      v0 = *(const u16x8*)vp; v1 = *(const u16x8*)(vp + 8);
    }

    const float dch = dchA[i];
    f32x4 s[4];
#pragma unroll
    for (int ni = 0; ni < 4; ++ni) s[ni] = (f32x4){0.f, 0.f, 0.f, 0.f};
#pragma unroll
    for (int kk = 0; kk < 2; ++kk) {
      bf16x8 av = ldsw(VTl, 16 * w + la, kk * 32 + kb8);
#pragma unroll
      for (int ni = 0; ni < 4; ++ni)
        s[ni] = __builtin_amdgcn_mfma_f32_16x16x32_bf16(
            av, ldsw(KT, 16 * ni + la, kk * 32 + kb8), s[ni], 0, 0, 0);
    }

    u16* Sc = Sbuf + (size_t)blkc * 4096;
#pragma unroll
    for (int ni = 0; ni < 4; ++ni)
#pragma unroll
      for (int rr = 0; rr < 4; ++rr)
        Sc[(dw + rr) * 64 + 16 * ni + la] = f2bf(run[ni][rr]);
#pragma unroll
    for (int ni = 0; ni < 4; ++ni)
#pragma unroll
      for (int rr = 0; rr < 4; ++rr)
        run[ni][rr] = dch * run[ni][rr] + s[ni][rr];

    {
      float zp = 0.f;
#pragma unroll
      for (int i2 = 0; i2 < 16; ++i2)
        zp += bf2f(KT[dkz * 64 + ((tqz + i2) ^ swkz)]);
      zp += __shfl_xor(zp, 1);
      zp += __shfl_xor(zp, 2);
      if ((tid & 3) == 0) zbuf[(size_t)blkc * 64 + dkz] = zrun;
      zrun = dch * zrun + zp;
    }
  }

  float* Ga = GAgg + ((size_t)bh * NGRP + g) * 4096;
#pragma unroll
  for (int ni = 0; ni < 4; ++ni)
#pragma unroll
    for (int rr = 0; rr < 4; ++rr)
      Ga[(dw + rr) * 64 + 16 * ni + la] = run[ni][rr];
  if ((tid & 3) == 0)
    zGAgg[((size_t)bh * NGRP + g) * 64 + dkz] = zrun;
}

// ---------------------------------------------------------------------------
// Scan level 2: across the 16 group aggregates. GAgg(f32) -> GBeg (bf16).
// ---------------------------------------------------------------------------
__global__ __launch_bounds__(1024)
void scan_top(const float* __restrict__ GAgg, u16* __restrict__ GBeg,
              float* __restrict__ zGAgg, const float* __restrict__ cAbuf) {
  const int bh = blockIdx.x;
  const size_t cb = (size_t)bh * CCHUNK;
  __shared__ float Dsh[NGRP];
  if (threadIdx.x < NGRP) {
    float s = 0.f;
#pragma unroll
    for (int i = 0; i < GCH; ++i)
      s += cAbuf[(cb + threadIdx.x * GCH + i) * 64 + 63];
    Dsh[threadIdx.x] = __expf(s);
  }
  __syncthreads();
  const int elem = threadIdx.x * 4;
  const float* base = GAgg + (size_t)bh * NGRP * 4096;
  u16* gb = GBeg + (size_t)bh * NGRP * 4096;
  f32x4 run = (f32x4){0.f, 0.f, 0.f, 0.f};
  f32x4 cur = *(const f32x4*)&base[elem];
#pragma unroll
  for (int gg = 0; gg < NGRP; ++gg) {
    f32x4 nxt;
    if (gg + 1 < NGRP) nxt = *(const f32x4*)&base[(gg + 1) * 4096 + elem];
    u16x4 o;
#pragma unroll
    for (int jj = 0; jj < 4; ++jj) o[jj] = f2bf(run[jj]);
    *(u16x4*)&gb[gg * 4096 + elem] = o;
    const float D = Dsh[gg];
#pragma unroll
    for (int jj = 0; jj < 4; ++jj) run[jj] = D * run[jj] + cur[jj];
    cur = nxt;
  }
  if (threadIdx.x < 64) {
    float* zb = zGAgg + (size_t)bh * NGRP * 64;
    float zr = 0.f;
#pragma unroll
    for (int gg = 0; gg < NGRP; ++gg) {
      float a = zb[gg * 64 + threadIdx.x];
      zb[gg * 64 + threadIdx.x] = zr;
      zr = Dsh[gg] * zr + a;
    }
  }
}

// ---------------------------------------------------------------------------
// Kernel C (MFMA): per-chunk output.
// ---------------------------------------------------------------------------
__global__ __launch_bounds__(256)
void chunk_out(u16* __restrict__ qb, const u16* __restrict__ kb,
               const u16* __restrict__ vb, const u16* __restrict__ Sbuf,
               const float* __restrict__ zbuf, const float* __restrict__ cAbuf,
               const u16* __restrict__ GBeg, const float* __restrict__ zGAgg,
               const float* __restrict__ dpbuf) {
  const int blk = blockIdx.x;
  const int c = blk & (CCHUNK - 1);
  const int h = (blk >> 7) & (HH - 1);
  const int b = blk >> 11;
  const int bh = blk >> 7;
  const int g = c >> 3;
  const int rowbase = b * NNLEN + c * LCH;

  __shared__ __align__(16) u16 Qs[64 * 64];
  __shared__ __align__(16) u16 Ke[64 * 64];   // Ke, later reused as P tile
  __shared__ __align__(16) u16 VT[64 * 64];
  __shared__ __align__(16) u16 STs[64 * 64];
  __shared__ float cAsh[64], zsh[64], denP[64], qzs[64];

  const int tid = threadIdx.x;
  const int r = tid >> 2, e = (tid & 3) * 16;
  const float dp = dpbuf[blk];

  const u16* qp = qb + (size_t)(rowbase + r) * PP + h * DH + e;
  const u16* kp = kb + (size_t)(rowbase + r) * PP + h * DH + e;
  const u16* vp = vb + (size_t)(rowbase + r) * PP + h * DH + e;
  u16x8 q0 = *(const u16x8*)qp, q1 = *(const u16x8*)(qp + 8);
  u16x8 k0 = *(const u16x8*)kp, k1 = *(const u16x8*)(kp + 8);
  u16x8 v0 = *(const u16x8*)vp, v1 = *(const u16x8*)(vp + 8);
  const u16* sp = Sbuf + (size_t)blk * 4096 + r * 64 + e;
  u16x8 p0 = *(const u16x8*)sp, p1 = *(const u16x8*)(sp + 8);
  const u16* gp = GBeg + ((size_t)bh * NGRP + g) * 4096 + r * 64 + e;
  u16x8 gb0 = *(const u16x8*)gp, gb1 = *(const u16x8*)(gp + 8);
  if (tid < 64) {
    cAsh[tid] = cAbuf[(size_t)blk * 64 + tid];
    zsh[tid] = zbuf[(size_t)blk * 64 + tid]
             + dp * zGAgg[((size_t)bh * NGRP + g) * 64 + tid];
  }
  __syncthreads();

  {
    const float c0c = cAsh[31];
    const int sw = (r & 7) << 3;
    const float qsc = __expf(cAsh[r] - c0c);
    const float ksc = __expf(c0c - cAsh[r]);
    const float ssc = __expf(c0c);
    u16x8 t0, t1, u0, u1, w0, w1;
#pragma unroll
    for (int j = 0; j < 8; ++j) {
      t0[j] = f2bf(bf2f(q0[j]) * qsc);
      t1[j] = f2bf(bf2f(q1[j]) * qsc);
      u0[j] = f2bf(bf2f(k0[j]) * ksc);
      u1[j] = f2bf(bf2f(k1[j]) * ksc);
    }
#pragma unroll
    for (int j = 0; j < 8; ++j) {
      w0[j] = f2bf((bf2f(p0[j]) + dp * bf2f(gb0[j])) * ssc);
      w1[j] = f2bf((bf2f(p1[j]) + dp * bf2f(gb1[j])) * ssc);
    }
    *(u16x8*)&Qs[r * 64 + (e ^ sw)] = t0;
    *(u16x8*)&Qs[r * 64 + ((e + 8) ^ sw)] = t1;
    *(u16x8*)&Ke[r * 64 + (e ^ sw)] = u0;
    *(u16x8*)&Ke[r * 64 + ((e + 8) ^ sw)] = u1;
    *(u16x8*)&STs[r * 64 + (e ^ sw)] = w0;
    *(u16x8*)&STs[r * 64 + ((e + 8) ^ sw)] = w1;
#pragma unroll
    for (int j = 0; j < 8; ++j) {
      int d0 = e + j, d1 = e + 8 + j;
      VT[d0 * 64 + (r ^ ((d0 & 7) << 3))] = v0[j];
      VT[d1 * 64 + (r ^ ((d1 & 7) << 3))] = v1[j];
    }
    if (tid < 64) zsh[tid] *= ssc;
  }
  __syncthreads();

  const int l = tid & 63, w = tid >> 6;
  const int kb8 = (l >> 4) << 3, la = l & 15;

  // --- MFMA1: P = Qe @ Ke^T ---
  bf16x8 aq[2];
  f32x4 p[4];
#pragma unroll
  for (int ni = 0; ni < 4; ++ni) p[ni] = (f32x4){0.f, 0.f, 0.f, 0.f};
#pragma unroll
  for (int kk = 0; kk < 2; ++kk) {
    aq[kk] = ldsw(Qs, 16 * w + la, kk * 32 + kb8);
#pragma unroll
    for (int ni = 0; ni < 4; ++ni)
      p[ni] = __builtin_amdgcn_mfma_f32_16x16x32_bf16(
          aq[kk], ldsw(Ke, 16 * ni + la, kk * 32 + kb8), p[ni], 0, 0, 0);
  }

  const int tw = 16 * w + ((l >> 4) << 2);
  float rsum[4] = {0.f, 0.f, 0.f, 0.f};
#pragma unroll
  for (int ni = 0; ni < 4; ++ni)
#pragma unroll
    for (int rr = 0; rr < 4; ++rr) {
      int s = 16 * ni + la, t = tw + rr;
      float v = (s <= t) ? p[ni][rr] : 0.f;
      p[ni][rr] = v;
      rsum[rr] += v;
    }
#pragma unroll
  for (int d = 1; d < 16; d <<= 1)
#pragma unroll
    for (int rr = 0; rr < 4; ++rr) rsum[rr] += __shfl_xor(rsum[rr], d);
  if (la == 0)
#pragma unroll
    for (int rr = 0; rr < 4; ++rr) denP[tw + rr] = rsum[rr];

  {
    float qzp = 0.f;
#pragma unroll
    for (int kk = 0; kk < 2; ++kk)
#pragma unroll
      for (int j = 0; j < 8; ++j) {
        union { bf16x8 b; u16x8 u; } cv; cv.b = aq[kk];
        qzp += bf2f(cv.u[j]) * zsh[kk * 32 + kb8 + j];
      }
    qzp += __shfl_xor(qzp, 16);
    qzp += __shfl_xor(qzp, 32);
    if (l < 16) qzs[16 * w + la] = qzp;
  }
  __syncthreads();

#pragma unroll
  for (int ni = 0; ni < 4; ++ni)
#pragma unroll
    for (int rr = 0; rr < 4; ++rr) {
      int t = tw + rr, s = 16 * ni + la;
      Ke[t * 64 + (s ^ ((t & 7) << 3))] = f2bf(p[ni][rr]);
    }
  __syncthreads();

  // --- MFMA2: O = P@V + Qe@S0e^T ---
  f32x4 o[4];
#pragma unroll
  for (int ni = 0; ni < 4; ++ni) o[ni] = (f32x4){0.f, 0.f, 0.f, 0.f};
#pragma unroll
  for (int kk = 0; kk < 2; ++kk) {
    bf16x8 ap = ldsw(Ke, 16 * w + la, kk * 32 + kb8);
#pragma unroll
    for (int ni = 0; ni < 4; ++ni)
      o[ni] = __builtin_amdgcn_mfma_f32_16x16x32_bf16(
          ap, ldsw(VT, 16 * ni + la, kk * 32 + kb8), o[ni], 0, 0, 0);
  }
#pragma unroll
  for (int kk = 0; kk < 2; ++kk)
#pragma unroll
    for (int ni = 0; ni < 4; ++ni)
      o[ni] = __builtin_amdgcn_mfma_f32_16x16x32_bf16(
          aq[kk], ldsw(STs, 16 * ni + la, kk * 32 + kb8), o[ni], 0, 0, 0);

  float dn[4];
#pragma unroll
  for (int rr = 0; rr < 4; ++rr) dn[rr] = qzs[tw + rr] + denP[tw + rr] + EPSV;
#pragma unroll
  for (int ni = 0; ni < 4; ++ni)
#pragma unroll
    for (int rr = 0; rr < 4; ++rr) {
      int t = tw + rr, dv = 16 * ni + la;
      qb[(size_t)(rowbase + t) * PP + h * DH + dv] = f2bf(o[ni][rr] / dn[rr]);
    }
}

// ---------------------------------------------------------------------------
extern "C" void kernel_launch(void* const* d_in, const int* in_sizes, int n_in,
                              void* d_out, int out_size, void* d_ws, size_t ws_size,
                              hipStream_t stream) {
  const float* x  = (const float*)d_in[0];
  const float* Wq = (const float*)d_in[1];
  const float* Wk = (const float*)d_in[2];
  const float* Wv = (const float*)d_in[3];
  const float* Wo = (const float*)d_in[4];
  const float* Wa = (const float*)d_in[5];
  const float* ba = (const float*)d_in[6];

  char* ws = (char*)d_ws;
  size_t off = 0;
  auto carve = [&](size_t bytes) {
    void* p = ws + off;
    off += (bytes + 255) & ~(size_t)255;
    return p;
  };
  u16* xb   = (u16*)carve((size_t)MM * DD * 2);
  u16* WqT  = (u16*)carve((size_t)PP * DD * 2);  // WqT/WkT/WvT contiguous
  u16* WkT  = (u16*)carve((size_t)PP * DD * 2);
  u16* WvT  = (u16*)carve((size_t)PP * DD * 2);
  u16* WoT  = (u16*)carve((size_t)DD * PP * 2);
  u16* WaT  = (u16*)carve((size_t)HH * DD * 2);
  u16* qb   = (u16*)carve((size_t)MM * PP * 2);  // qb/kb/vb contiguous
  u16* kb   = (u16*)carve((size_t)MM * PP * 2);
  u16* vb   = (u16*)carve((size_t)MM * PP * 2);
  float* abuf  = (float*)carve((size_t)MM * HH * 4);
  u16*  Sbuf   = (u16*)carve((size_t)BBATCH * HH * CCHUNK * 4096 * 2);
  float* zbuf  = (float*)carve((size_t)BBATCH * HH * CCHUNK * 64 * 4);
  float* cAbuf = (float*)carve((size_t)BBATCH * HH * CCHUNK * 64 * 4);
  float* GAgg  = (float*)carve((size_t)BBATCH * HH * NGRP * 4096 * 4);
  u16*  GBeg   = (u16*)carve((size_t)BBATCH * HH * NGRP * 4096 * 2);
  float* zGAgg = (float*)carve((size_t)BBATCH * HH * NGRP * 64 * 4);
  float* dpbuf = (float*)carve((size_t)BBATCH * HH * CCHUNK * 4);

  prep_all<<<12352, 256, 0, stream>>>(x, xb, Wq, WqT, Wk, WkT, Wv, WvT,
                                      Wo, WoT, Wa, WaT);

  // fused QKV (768 gemm blocks) + a_proj tail (64 blocks)
  gemm_db<12, 768, 1><<<768 + MM / 256, 512, 0, stream>>>(
      xb, WqT, qb, WaT, ba, abuf);

  chunk_local_scan<<<BBATCH * HH * NGRP, 256, 0, stream>>>(
      kb, vb, abuf, Sbuf, zbuf, cAbuf, GAgg, zGAgg, dpbuf);
  scan_top<<<BBATCH * HH, 1024, 0, stream>>>(GAgg, GBeg, zGAgg, cAbuf);
  chunk_out<<<BBATCH * HH * CCHUNK, 256, 0, stream>>>(qb, kb, vb, Sbuf, zbuf, cAbuf,
                                                      GBeg, zGAgg, dpbuf);

  gemm_db<4, 256, 0><<<256, 512, 0, stream>>>(qb, WoT, (float*)d_out,
                                              nullptr, nullptr, nullptr);
}

// Round 13
// 243.688 us; speedup vs baseline: 1.0864x; 1.0109x over previous
//
#include <hip/hip_runtime.h>
#include <stdint.h>

#define HH 16
#define DH 64
#define DD 1024
#define PP 1024
#define NNLEN 8192
#define BBATCH 2
#define MM (BBATCH*NNLEN)   // 16384 rows
#define CCHUNK 128          // chunks per (b,h)
#define LCH 64              // chunk length
#define NGRP 16             // scan groups per (b,h)
#define GCH 8               // chunks per group
#define EPSV 1e-6f

typedef unsigned short u16;
typedef __attribute__((ext_vector_type(4))) unsigned short u16x4;
typedef __attribute__((ext_vector_type(8))) unsigned short u16x8;
typedef __attribute__((ext_vector_type(8))) __bf16 bf16x8;
typedef __attribute__((ext_vector_type(4))) float f32x4;

__device__ __forceinline__ u16 f2bf(float f) {
  unsigned x = __float_as_uint(f);
  return (u16)((x + 0x7fffu + ((x >> 16) & 1u)) >> 16);
}
__device__ __forceinline__ float bf2f(u16 u) {
  return __uint_as_float(((unsigned)u) << 16);
}

// async global->LDS, 16B per lane. LDS dest must be wave-uniform base.
__device__ __forceinline__ void gl2lds16(const void* g, void* l) {
  __builtin_amdgcn_global_load_lds(
      reinterpret_cast<__attribute__((address_space(1))) void*>(
          reinterpret_cast<uintptr_t>(g)),
      reinterpret_cast<__attribute__((address_space(3))) void*>(
          reinterpret_cast<uintptr_t>(l)),
      16, 0, 0);
}

// swizzled LDS read of a bf16x8 fragment from a [*][64] u16 tile.
__device__ __forceinline__ bf16x8 ldsw(const u16* base, int row, int col) {
  union { u16x8 u; bf16x8 b; } cv;
  cv.u = *(const u16x8*)&base[row * 64 + (col ^ ((row & 7) << 3))];
  return cv.b;
}

// ---------------------------------------------------------------------------
// prep_all (single launch): x convert + 4 weight transposes + Wa transpose
// ---------------------------------------------------------------------------
__global__ __launch_bounds__(256)
void prep_all(const float* __restrict__ x, u16* __restrict__ xb,
              const float* __restrict__ Wq, u16* __restrict__ WqT,
              const float* __restrict__ Wk, u16* __restrict__ WkT,
              const float* __restrict__ Wv, u16* __restrict__ WvT,
              const float* __restrict__ Wo, u16* __restrict__ WoT,
              const float* __restrict__ Wa, u16* __restrict__ WaT) {
  __shared__ float tile[32][33];
  const int bid = blockIdx.x;
  const int tid = threadIdx.x;
  if (bid < 8192) {
    size_t i = ((size_t)bid * 256 + tid) * 8;
    f32x4 a = *(const f32x4*)(x + i);
    f32x4 b = *(const f32x4*)(x + i + 4);
    u16x8 o;
    o[0] = f2bf(a[0]); o[1] = f2bf(a[1]); o[2] = f2bf(a[2]); o[3] = f2bf(a[3]);
    o[4] = f2bf(b[0]); o[5] = f2bf(b[1]); o[6] = f2bf(b[2]); o[7] = f2bf(b[3]);
    *(u16x8*)(xb + i) = o;
    return;
  }
  if (bid < 12288) {
    const int t = (bid - 8192) >> 10;
    const int sub = (bid - 8192) & 1023;
    const float* in = (t == 0) ? Wq : (t == 1) ? Wk : (t == 2) ? Wv : Wo;
    u16* out = (t == 0) ? WqT : (t == 1) ? WkT : (t == 2) ? WvT : WoT;
    const int bx = (sub & 31) * 32, by = (sub >> 5) * 32;
    const int tx = tid & 31, ty = tid >> 5;
    for (int i2 = ty; i2 < 32; i2 += 8)
      tile[i2][tx] = in[(size_t)(by + i2) * 1024 + bx + tx];
    __syncthreads();
    for (int i2 = ty; i2 < 32; i2 += 8)
      out[(size_t)(bx + i2) * 1024 + by + tx] = f2bf(tile[tx][i2]);
    return;
  }
  {
    int idx = (bid - 12288) * 256 + tid;
    WaT[idx] = f2bf(Wa[(idx & 1023) * 16 + (idx >> 10)]);
  }
}

// ---------------------------------------------------------------------------
// bf16 MFMA GEMM, minimal-barrier double-buffer, STAGE-FIRST (r9-verified):
// 256x256 tile, BK=64, 8 waves, ONE vmcnt(0)+s_barrier per K-tile,
// r9 XCD swizzle. ROUTE=1: first NAP blocks run a fused a_proj (overlaps
// with the first GEMM wave), then NGT gemm blocks (fused QKV, N=3072,
// routed bf16 epilogue w/ elu+1 on q/k). ROUTE=0: f32 output (Wo).
// ---------------------------------------------------------------------------
template<int NCT, int NGT, int NAP, int ROUTE>
__global__ __launch_bounds__(512)
void gemm_db(const u16* __restrict__ A, const u16* __restrict__ Bt,
             void* __restrict__ Cout, const u16* __restrict__ WaT,
             const float* __restrict__ ba, float* __restrict__ abuf) {
  __shared__ __align__(16) u16 As[2][256 * 64];
  __shared__ __align__(16) u16 Bs[2][256 * 64];
  const int tid = threadIdx.x;
  const int l = tid & 63;
  const int wid = tid >> 6;       // 0..7
  const int la = l & 15, kb8 = (l >> 4) * 8;
  const int K = 1024;

  if (ROUTE && blockIdx.x < NAP) {
    // ---- fused a_proj (front blocks): 256 rows per block, 8 waves, BK=32
    const int brow2 = blockIdx.x * 256;
    const int sr = tid >> 2, se = (tid & 3) * 8;
    u16* As0 = As[0];
    u16* Bs0 = Bs[0];
    f32x4 acc2[2];
    acc2[0] = (f32x4){0.f, 0.f, 0.f, 0.f};
    acc2[1] = (f32x4){0.f, 0.f, 0.f, 0.f};
    for (int kt = 0; kt < 32; ++kt) {
      const int k0 = kt * 32;
      __syncthreads();
      gl2lds16(A + (size_t)(brow2 + sr) * DD + k0 + se, &As0[wid * 512]);
      gl2lds16(A + (size_t)(brow2 + 128 + sr) * DD + k0 + se,
               &As0[4096 + wid * 512]);
      if (wid == 0)
        gl2lds16(WaT + (size_t)(l >> 2) * DD + k0 + (l & 3) * 8, &Bs0[0]);
      __syncthreads();
      union { u16x8 u; bf16x8 b; } cvb;
      cvb.u = *(const u16x8*)&Bs0[la * 32 + kb8];
#pragma unroll
      for (int mi = 0; mi < 2; ++mi) {
        union { u16x8 u; bf16x8 b; } cva;
        cva.u = *(const u16x8*)&As0[(wid * 32 + mi * 16 + la) * 32 + kb8];
        acc2[mi] = __builtin_amdgcn_mfma_f32_16x16x32_bf16(cva.b, cvb.b, acc2[mi], 0, 0, 0);
      }
    }
    const float bav = ba[la];
#pragma unroll
    for (int mi = 0; mi < 2; ++mi)
#pragma unroll
      for (int rr = 0; rr < 4; ++rr) {
        int row = brow2 + wid * 32 + mi * 16 + ((l >> 4) << 2) + rr;
        float t = acc2[mi][rr] + bav + 2.0f;
        abuf[(size_t)row * HH + la] = 1.f / (1.f + __expf(-t));
      }
    return;
  }

  // r9 XCD swizzle over the NGT gemm blocks
  const int f = ROUTE ? (blockIdx.x - NAP) : blockIdx.x;
  const int swz = (f & 7) * (NGT >> 3) + (f >> 3);
  const int brow = (swz / NCT) * 256;
  const int bcol = (swz % NCT) * 256;
  const int wr = wid >> 2;        // 0..1  (M half)
  const int wc = wid & 3;         // 0..3  (N quarter)
  const int srow = l >> 3;                       // row within 8-row chunk
  const int scol = ((l & 7) * 8) ^ (srow << 3);  // pre-swizzled global col
  const int ldso = (wid * 2) * 512;              // wave chunk base within half

  f32x4 acc[8][4];
#pragma unroll
  for (int i = 0; i < 8; ++i)
#pragma unroll
    for (int j = 0; j < 4; ++j) acc[i][j] = (f32x4){0.f, 0.f, 0.f, 0.f};

  // prologue: stage K-tile 0 into buf 0
#pragma unroll
  for (int h = 0; h < 2; ++h)
#pragma unroll
    for (int j = 0; j < 2; ++j) {
      const int r0 = h * 128 + (wid * 2 + j) * 8 + srow;
      gl2lds16(A  + (size_t)(brow + r0) * K + scol, &As[0][h * 8192 + ldso + j * 512]);
      gl2lds16(Bt + (size_t)(bcol + r0) * K + scol, &Bs[0][h * 8192 + ldso + j * 512]);
    }
  asm volatile("s_waitcnt vmcnt(0)" ::: "memory");
  __builtin_amdgcn_s_barrier();

  const int NKT = K / 64;
  for (int kt = 0; kt < NKT; ++kt) {
    const u16* lA = As[kt & 1];
    const u16* lB = Bs[kt & 1];
    u16* nA = As[(kt + 1) & 1];
    u16* nB = Bs[(kt + 1) & 1];
    const int knext = (kt + 1) * 64;
    const bool more = (kt + 1 < NKT);

    // stage next K-tile FIRST: the whole tile's compute covers the latency.
    if (more) {
#pragma unroll
      for (int h = 0; h < 2; ++h)
#pragma unroll
        for (int j = 0; j < 2; ++j) {
          const int r0 = h * 128 + (wid * 2 + j) * 8 + srow;
          gl2lds16(A  + (size_t)(brow + r0) * K + knext + scol,
                   nA + h * 8192 + ldso + j * 512);
          gl2lds16(Bt + (size_t)(bcol + r0) * K + knext + scol,
                   nB + h * 8192 + ldso + j * 512);
        }
    }

    bf16x8 af[4][2], bfr[4][2];
#pragma unroll
    for (int m2 = 0; m2 < 4; ++m2)
#pragma unroll
      for (int kk = 0; kk < 2; ++kk)
        af[m2][kk] = ldsw(lA, wr * 128 + m2 * 16 + la, kk * 32 + kb8);
#pragma unroll
    for (int n2 = 0; n2 < 4; ++n2)
#pragma unroll
      for (int kk = 0; kk < 2; ++kk)
        bfr[n2][kk] = ldsw(lB, wc * 64 + n2 * 16 + la, kk * 32 + kb8);

    __builtin_amdgcn_s_setprio(1);
#pragma unroll
    for (int m2 = 0; m2 < 4; ++m2)
#pragma unroll
      for (int n2 = 0; n2 < 4; ++n2)
#pragma unroll
        for (int kk = 0; kk < 2; ++kk)
          acc[m2][n2] = __builtin_amdgcn_mfma_f32_16x16x32_bf16(
              af[m2][kk], bfr[n2][kk], acc[m2][n2], 0, 0, 0);
    __builtin_amdgcn_s_setprio(0);

    // fragments: M-half 1 (reuse af regs; bfr persists)
#pragma unroll
    for (int m2 = 0; m2 < 4; ++m2)
#pragma unroll
      for (int kk = 0; kk < 2; ++kk)
        af[m2][kk] = ldsw(lA, wr * 128 + 64 + m2 * 16 + la, kk * 32 + kb8);

    __builtin_amdgcn_s_setprio(1);
#pragma unroll
    for (int m2 = 0; m2 < 4; ++m2)
#pragma unroll
      for (int n2 = 0; n2 < 4; ++n2)
#pragma unroll
        for (int kk = 0; kk < 2; ++kk)
          acc[4 + m2][n2] = __builtin_amdgcn_mfma_f32_16x16x32_bf16(
              af[m2][kk], bfr[n2][kk], acc[4 + m2][n2], 0, 0, 0);
    __builtin_amdgcn_s_setprio(0);

    if (more) {
      asm volatile("s_waitcnt vmcnt(0)" ::: "memory");
      __builtin_amdgcn_s_barrier();
    }
  }

  const int wrow = wr * 128, wcol = wc * 64;
  if (ROUTE) {
    u16* base = (u16*)Cout + (size_t)(bcol >> 10) * ((size_t)MM * 1024);
    const bool act = (bcol < 2048);
#pragma unroll
    for (int mi = 0; mi < 8; ++mi)
#pragma unroll
      for (int ni = 0; ni < 4; ++ni)
#pragma unroll
        for (int rr = 0; rr < 4; ++rr) {
          int row = brow + wrow + mi * 16 + ((l >> 4) << 2) + rr;
          int c2 = (bcol & 1023) + wcol + ni * 16 + la;
          float v = acc[mi][ni][rr];
          if (act) v = v > 0.f ? v + 1.f : __expf(v);
          base[(size_t)row * 1024 + c2] = f2bf(v);
        }
  } else {
#pragma unroll
    for (int mi = 0; mi < 8; ++mi)
#pragma unroll
      for (int ni = 0; ni < 4; ++ni)
#pragma unroll
        for (int rr = 0; rr < 4; ++rr) {
          int row = brow + wrow + mi * 16 + ((l >> 4) << 2) + rr;
          int col = bcol + wcol + ni * 16 + la;
          ((float*)Cout)[(size_t)row * 1024 + col] = acc[mi][ni][rr];
        }
  }
}

// ---------------------------------------------------------------------------
// FUSED Kernel A + scan level 1, cA-hoisted + k/v software pipeline.
// ---------------------------------------------------------------------------
__global__ __launch_bounds__(256)
void chunk_local_scan(const u16* __restrict__ kb, const u16* __restrict__ vb,
                      const float* __restrict__ abuf,
                      u16* __restrict__ Sbuf, float* __restrict__ zbuf,
                      float* __restrict__ cAbuf,
                      float* __restrict__ GAgg, float* __restrict__ zGAgg,
                      float* __restrict__ dpbuf) {
  const int g = blockIdx.x & (NGRP - 1);
  const int bh = blockIdx.x >> 4;
  const int h = bh & (HH - 1);
  const int b = bh >> 4;
  __shared__ __align__(16) u16 KT[64 * 64];
  __shared__ __align__(16) u16 VTl[64 * 64];
  __shared__ float wshA[GCH][64];
  __shared__ float dchA[GCH];
  const int tid = threadIdx.x;
  const int r = tid >> 2, e = (tid & 3) * 16;
  const int l = tid & 63, w = tid >> 6;
  const int kb8 = (l >> 4) << 3, la = l & 15;
  const int dw = 16 * w + ((l >> 4) << 2);
  const int dkz = tid >> 2, tqz = (tid & 3) * 16, swkz = (dkz & 7) << 3;
  const int c0 = g * GCH;
  const int rowbase0 = b * NNLEN + c0 * LCH;

#pragma unroll
  for (int ii = 0; ii < 2; ++ii) {
    const int i = w * 2 + ii;
    const int blkc = bh * CCHUNK + c0 + i;
    float v = __logf(abuf[(size_t)(rowbase0 + i * LCH + l) * HH + h]);
#pragma unroll
    for (int d = 1; d < 64; d <<= 1) {
      float u = __shfl_up(v, d);
      if (l >= d) v += u;
    }
    cAbuf[(size_t)blkc * 64 + l] = v;
    float tot = __shfl(v, 63);
    wshA[i][l] = __expf(tot - v);
    if (l == 0) dchA[i] = __expf(tot);
  }
  __syncthreads();
  if (tid == 0) {
    float rp = 1.f;
#pragma unroll
    for (int i = 0; i < GCH; ++i) {
      dpbuf[bh * CCHUNK + c0 + i] = rp;
      rp *= dchA[i];
    }
  }

  f32x4 run[4];
#pragma unroll
  for (int ni = 0; ni < 4; ++ni) run[ni] = (f32x4){0.f, 0.f, 0.f, 0.f};
  float zrun = 0.f;

  const u16* kp = kb + (size_t)(rowbase0 + r) * PP + h * DH + e;
  const u16* vp = vb + (size_t)(rowbase0 + r) * PP + h * DH + e;
  u16x8 k0 = *(const u16x8*)kp, k1 = *(const u16x8*)(kp + 8);
  u16x8 v0 = *(const u16x8*)vp, v1 = *(const u16x8*)(vp + 8);

  for (int i = 0; i < GCH; ++i) {
    const int blkc = bh * CCHUNK + c0 + i;
    if (i) __syncthreads();

    {
      const float wt = wshA[i][r];
#pragma unroll
      for (int j = 0; j < 8; ++j) {
        int d0 = e + j, d1 = e + 8 + j;
        KT[d0 * 64 + (r ^ ((d0 & 7) << 3))] = f2bf(bf2f(k0[j]) * wt);
        KT[d1 * 64 + (r ^ ((d1 & 7) << 3))] = f2bf(bf2f(k1[j]) * wt);
        VTl[d0 * 64 + (r ^ ((d0 & 7) << 3))] = v0[j];
        VTl[d1 * 64 + (r ^ ((d1 & 7) << 3))] = v1[j];
      }
    }
    __syncthreads();

    if (i + 1 < GCH) {
      const int rb = rowbase0 + (i + 1) * LCH;
      kp = kb + (size_t)(rb + r) * PP + h * DH + e;
      vp = vb + (size_t)(rb + r) * PP + h * DH + e;
      k0 = *(const u16x8*)kp; k1 = *(const u16x8*)(kp + 8);
      v0 = *(const u16x8*)vp; v1 = *(const u16x8*)(vp + 8);
    }

    const float dch = dchA[i];
    f32x4 s[4];
#pragma unroll
    for (int ni = 0; ni < 4; ++ni) s[ni] = (f32x4){0.f, 0.f, 0.f, 0.f};
#pragma unroll
    for (int kk = 0; kk < 2; ++kk) {
      bf16x8 av = ldsw(VTl, 16 * w + la, kk * 32 + kb8);
#pragma unroll
      for (int ni = 0; ni < 4; ++ni)
        s[ni] = __builtin_amdgcn_mfma_f32_16x16x32_bf16(
            av, ldsw(KT, 16 * ni + la, kk * 32 + kb8), s[ni], 0, 0, 0);
    }

    u16* Sc = Sbuf + (size_t)blkc * 4096;
#pragma unroll
    for (int ni = 0; ni < 4; ++ni)
#pragma unroll
      for (int rr = 0; rr < 4; ++rr)
        Sc[(dw + rr) * 64 + 16 * ni + la] = f2bf(run[ni][rr]);
#pragma unroll
    for (int ni = 0; ni < 4; ++ni)
#pragma unroll
      for (int rr = 0; rr < 4; ++rr)
        run[ni][rr] = dch * run[ni][rr] + s[ni][rr];

    {
      float zp = 0.f;
#pragma unroll
      for (int i2 = 0; i2 < 16; ++i2)
        zp += bf2f(KT[dkz * 64 + ((tqz + i2) ^ swkz)]);
      zp += __shfl_xor(zp, 1);
      zp += __shfl_xor(zp, 2);
      if ((tid & 3) == 0) zbuf[(size_t)blkc * 64 + dkz] = zrun;
      zrun = dch * zrun + zp;
    }
  }

  float* Ga = GAgg + ((size_t)bh * NGRP + g) * 4096;
#pragma unroll
  for (int ni = 0; ni < 4; ++ni)
#pragma unroll
    for (int rr = 0; rr < 4; ++rr)
      Ga[(dw + rr) * 64 + 16 * ni + la] = run[ni][rr];
  if ((tid & 3) == 0)
    zGAgg[((size_t)bh * NGRP + g) * 64 + dkz] = zrun;
}

// ---------------------------------------------------------------------------
// Scan level 2: across the 16 group aggregates. GAgg(f32) -> GBeg (bf16).
// ---------------------------------------------------------------------------
__global__ __launch_bounds__(1024)
void scan_top(const float* __restrict__ GAgg, u16* __restrict__ GBeg,
              float* __restrict__ zGAgg, const float* __restrict__ cAbuf) {
  const int bh = blockIdx.x;
  const size_t cb = (size_t)bh * CCHUNK;
  __shared__ float Dsh[NGRP];
  if (threadIdx.x < NGRP) {
    float s = 0.f;
#pragma unroll
    for (int i = 0; i < GCH; ++i)
      s += cAbuf[(cb + threadIdx.x * GCH + i) * 64 + 63];
    Dsh[threadIdx.x] = __expf(s);
  }
  __syncthreads();
  const int elem = threadIdx.x * 4;
  const float* base = GAgg + (size_t)bh * NGRP * 4096;
  u16* gb = GBeg + (size_t)bh * NGRP * 4096;
  f32x4 run = (f32x4){0.f, 0.f, 0.f, 0.f};
  f32x4 cur = *(const f32x4*)&base[elem];
#pragma unroll
  for (int gg = 0; gg < NGRP; ++gg) {
    f32x4 nxt;
    if (gg + 1 < NGRP) nxt = *(const f32x4*)&base[(gg + 1) * 4096 + elem];
    u16x4 o;
#pragma unroll
    for (int jj = 0; jj < 4; ++jj) o[jj] = f2bf(run[jj]);
    *(u16x4*)&gb[gg * 4096 + elem] = o;
    const float D = Dsh[gg];
#pragma unroll
    for (int jj = 0; jj < 4; ++jj) run[jj] = D * run[jj] + cur[jj];
    cur = nxt;
  }
  if (threadIdx.x < 64) {
    float* zb = zGAgg + (size_t)bh * NGRP * 64;
    float zr = 0.f;
#pragma unroll
    for (int gg = 0; gg < NGRP; ++gg) {
      float a = zb[gg * 64 + threadIdx.x];
      zb[gg * 64 + threadIdx.x] = zr;
      zr = Dsh[gg] * zr + a;
    }
  }
}

// ---------------------------------------------------------------------------
// Kernel C (MFMA): per-chunk output.
// ---------------------------------------------------------------------------
__global__ __launch_bounds__(256)
void chunk_out(u16* __restrict__ qb, const u16* __restrict__ kb,
               const u16* __restrict__ vb, const u16* __restrict__ Sbuf,
               const float* __restrict__ zbuf, const float* __restrict__ cAbuf,
               const u16* __restrict__ GBeg, const float* __restrict__ zGAgg,
               const float* __restrict__ dpbuf) {
  const int blk = blockIdx.x;
  const int c = blk & (CCHUNK - 1);
  const int h = (blk >> 7) & (HH - 1);
  const int b = blk >> 11;
  const int bh = blk >> 7;
  const int g = c >> 3;
  const int rowbase = b * NNLEN + c * LCH;

  __shared__ __align__(16) u16 Qs[64 * 64];
  __shared__ __align__(16) u16 Ke[64 * 64];   // Ke, later reused as P tile
  __shared__ __align__(16) u16 VT[64 * 64];
  __shared__ __align__(16) u16 STs[64 * 64];
  __shared__ float cAsh[64], zsh[64], denP[64], qzs[64];

  const int tid = threadIdx.x;
  const int r = tid >> 2, e = (tid & 3) * 16;
  const float dp = dpbuf[blk];

  const u16* qp = qb + (size_t)(rowbase + r) * PP + h * DH + e;
  const u16* kp = kb + (size_t)(rowbase + r) * PP + h * DH + e;
  const u16* vp = vb + (size_t)(rowbase + r) * PP + h * DH + e;
  u16x8 q0 = *(const u16x8*)qp, q1 = *(const u16x8*)(qp + 8);
  u16x8 k0 = *(const u16x8*)kp, k1 = *(const u16x8*)(kp + 8);
  u16x8 v0 = *(const u16x8*)vp, v1 = *(const u16x8*)(vp + 8);
  const u16* sp = Sbuf + (size_t)blk * 4096 + r * 64 + e;
  u16x8 p0 = *(const u16x8*)sp, p1 = *(const u16x8*)(sp + 8);
  const u16* gp = GBeg + ((size_t)bh * NGRP + g) * 4096 + r * 64 + e;
  u16x8 gb0 = *(const u16x8*)gp, gb1 = *(const u16x8*)(gp + 8);
  if (tid < 64) {
    cAsh[tid] = cAbuf[(size_t)blk * 64 + tid];
    zsh[tid] = zbuf[(size_t)blk * 64 + tid]
             + dp * zGAgg[((size_t)bh * NGRP + g) * 64 + tid];
  }
  __syncthreads();

  {
    const float c0c = cAsh[31];
    const int sw = (r & 7) << 3;
    const float qsc = __expf(cAsh[r] - c0c);
    const float ksc = __expf(c0c - cAsh[r]);
    const float ssc = __expf(c0c);
    u16x8 t0, t1, u0, u1, w0, w1;
#pragma unroll
    for (int j = 0; j < 8; ++j) {
      t0[j] = f2bf(bf2f(q0[j]) * qsc);
      t1[j] = f2bf(bf2f(q1[j]) * qsc);
      u0[j] = f2bf(bf2f(k0[j]) * ksc);
      u1[j] = f2bf(bf2f(k1[j]) * ksc);
    }
#pragma unroll
    for (int j = 0; j < 8; ++j) {
      w0[j] = f2bf((bf2f(p0[j]) + dp * bf2f(gb0[j])) * ssc);
      w1[j] = f2bf((bf2f(p1[j]) + dp * bf2f(gb1[j])) * ssc);
    }
    *(u16x8*)&Qs[r * 64 + (e ^ sw)] = t0;
    *(u16x8*)&Qs[r * 64 + ((e + 8) ^ sw)] = t1;
    *(u16x8*)&Ke[r * 64 + (e ^ sw)] = u0;
    *(u16x8*)&Ke[r * 64 + ((e + 8) ^ sw)] = u1;
    *(u16x8*)&STs[r * 64 + (e ^ sw)] = w0;
    *(u16x8*)&STs[r * 64 + ((e + 8) ^ sw)] = w1;
#pragma unroll
    for (int j = 0; j < 8; ++j) {
      int d0 = e + j, d1 = e + 8 + j;
      VT[d0 * 64 + (r ^ ((d0 & 7) << 3))] = v0[j];
      VT[d1 * 64 + (r ^ ((d1 & 7) << 3))] = v1[j];
    }
    if (tid < 64) zsh[tid] *= ssc;
  }
  __syncthreads();

  const int l = tid & 63, w = tid >> 6;
  const int kb8 = (l >> 4) << 3, la = l & 15;

  // --- MFMA1: P = Qe @ Ke^T ---
  bf16x8 aq[2];
  f32x4 p[4];
#pragma unroll
  for (int ni = 0; ni < 4; ++ni) p[ni] = (f32x4){0.f, 0.f, 0.f, 0.f};
#pragma unroll
  for (int kk = 0; kk < 2; ++kk) {
    aq[kk] = ldsw(Qs, 16 * w + la, kk * 32 + kb8);
#pragma unroll
    for (int ni = 0; ni < 4; ++ni)
      p[ni] = __builtin_amdgcn_mfma_f32_16x16x32_bf16(
          aq[kk], ldsw(Ke, 16 * ni + la, kk * 32 + kb8), p[ni], 0, 0, 0);
  }

  const int tw = 16 * w + ((l >> 4) << 2);
  float rsum[4] = {0.f, 0.f, 0.f, 0.f};
#pragma unroll
  for (int ni = 0; ni < 4; ++ni)
#pragma unroll
    for (int rr = 0; rr < 4; ++rr) {
      int s = 16 * ni + la, t = tw + rr;
      float v = (s <= t) ? p[ni][rr] : 0.f;
      p[ni][rr] = v;
      rsum[rr] += v;
    }
#pragma unroll
  for (int d = 1; d < 16; d <<= 1)
#pragma unroll
    for (int rr = 0; rr < 4; ++rr) rsum[rr] += __shfl_xor(rsum[rr], d);
  if (la == 0)
#pragma unroll
    for (int rr = 0; rr < 4; ++rr) denP[tw + rr] = rsum[rr];

  {
    float qzp = 0.f;
#pragma unroll
    for (int kk = 0; kk < 2; ++kk)
#pragma unroll
      for (int j = 0; j < 8; ++j) {
        union { bf16x8 b; u16x8 u; } cv; cv.b = aq[kk];
        qzp += bf2f(cv.u[j]) * zsh[kk * 32 + kb8 + j];
      }
    qzp += __shfl_xor(qzp, 16);
    qzp += __shfl_xor(qzp, 32);
    if (l < 16) qzs[16 * w + la] = qzp;
  }
  __syncthreads();

#pragma unroll
  for (int ni = 0; ni < 4; ++ni)
#pragma unroll
    for (int rr = 0; rr < 4; ++rr) {
      int t = tw + rr, s = 16 * ni + la;
      Ke[t * 64 + (s ^ ((t & 7) << 3))] = f2bf(p[ni][rr]);
    }
  __syncthreads();

  // --- MFMA2: O = P@V + Qe@S0e^T ---
  f32x4 o[4];
#pragma unroll
  for (int ni = 0; ni < 4; ++ni) o[ni] = (f32x4){0.f, 0.f, 0.f, 0.f};
#pragma unroll
  for (int kk = 0; kk < 2; ++kk) {
    bf16x8 ap = ldsw(Ke, 16 * w + la, kk * 32 + kb8);
#pragma unroll
    for (int ni = 0; ni < 4; ++ni)
      o[ni] = __builtin_amdgcn_mfma_f32_16x16x32_bf16(
          ap, ldsw(VT, 16 * ni + la, kk * 32 + kb8), o[ni], 0, 0, 0);
  }
#pragma unroll
  for (int kk = 0; kk < 2; ++kk)
#pragma unroll
    for (int ni = 0; ni < 4; ++ni)
      o[ni] = __builtin_amdgcn_mfma_f32_16x16x32_bf16(
          aq[kk], ldsw(STs, 16 * ni + la, kk * 32 + kb8), o[ni], 0, 0, 0);

  float dn[4];
#pragma unroll
  for (int rr = 0; rr < 4; ++rr) dn[rr] = qzs[tw + rr] + denP[tw + rr] + EPSV;
#pragma unroll
  for (int ni = 0; ni < 4; ++ni)
#pragma unroll
    for (int rr = 0; rr < 4; ++rr) {
      int t = tw + rr, dv = 16 * ni + la;
      qb[(size_t)(rowbase + t) * PP + h * DH + dv] = f2bf(o[ni][rr] / dn[rr]);
    }
}

// ---------------------------------------------------------------------------
extern "C" void kernel_launch(void* const* d_in, const int* in_sizes, int n_in,
                              void* d_out, int out_size, void* d_ws, size_t ws_size,
                              hipStream_t stream) {
  const float* x  = (const float*)d_in[0];
  const float* Wq = (const float*)d_in[1];
  const float* Wk = (const float*)d_in[2];
  const float* Wv = (const float*)d_in[3];
  const float* Wo = (const float*)d_in[4];
  const float* Wa = (const float*)d_in[5];
  const float* ba = (const float*)d_in[6];

  char* ws = (char*)d_ws;
  size_t off = 0;
  auto carve = [&](size_t bytes) {
    void* p = ws + off;
    off += (bytes + 255) & ~(size_t)255;
    return p;
  };
  u16* xb   = (u16*)carve((size_t)MM * DD * 2);
  u16* WqT  = (u16*)carve((size_t)PP * DD * 2);  // WqT/WkT/WvT contiguous
  u16* WkT  = (u16*)carve((size_t)PP * DD * 2);
  u16* WvT  = (u16*)carve((size_t)PP * DD * 2);
  u16* WoT  = (u16*)carve((size_t)DD * PP * 2);
  u16* WaT  = (u16*)carve((size_t)HH * DD * 2);
  u16* qb   = (u16*)carve((size_t)MM * PP * 2);  // qb/kb/vb contiguous
  u16* kb   = (u16*)carve((size_t)MM * PP * 2);
  u16* vb   = (u16*)carve((size_t)MM * PP * 2);
  float* abuf  = (float*)carve((size_t)MM * HH * 4);
  u16*  Sbuf   = (u16*)carve((size_t)BBATCH * HH * CCHUNK * 4096 * 2);
  float* zbuf  = (float*)carve((size_t)BBATCH * HH * CCHUNK * 64 * 4);
  float* cAbuf = (float*)carve((size_t)BBATCH * HH * CCHUNK * 64 * 4);
  float* GAgg  = (float*)carve((size_t)BBATCH * HH * NGRP * 4096 * 4);
  u16*  GBeg   = (u16*)carve((size_t)BBATCH * HH * NGRP * 4096 * 2);
  float* zGAgg = (float*)carve((size_t)BBATCH * HH * NGRP * 64 * 4);
  float* dpbuf = (float*)carve((size_t)BBATCH * HH * CCHUNK * 4);

  prep_all<<<12352, 256, 0, stream>>>(x, xb, Wq, WqT, Wk, WkT, Wv, WvT,
                                      Wo, WoT, Wa, WaT);

  // a_proj (64 front blocks, overlaps first GEMM wave) + fused QKV (768)
  gemm_db<12, 768, 64, 1><<<64 + 768, 512, 0, stream>>>(
      xb, WqT, qb, WaT, ba, abuf);

  chunk_local_scan<<<BBATCH * HH * NGRP, 256, 0, stream>>>(
      kb, vb, abuf, Sbuf, zbuf, cAbuf, GAgg, zGAgg, dpbuf);
  scan_top<<<BBATCH * HH, 1024, 0, stream>>>(GAgg, GBeg, zGAgg, cAbuf);
  chunk_out<<<BBATCH * HH * CCHUNK, 256, 0, stream>>>(qb, kb, vb, Sbuf, zbuf, cAbuf,
                                                      GBeg, zGAgg, dpbuf);

  gemm_db<4, 256, 0, 0><<<256, 512, 0, stream>>>(qb, WoT, (float*)d_out,
                                                 nullptr, nullptr, nullptr);
}